// Round 11
// baseline (1953.755 us; speedup 1.0000x reference)
//
#include <hip/hip_runtime.h>
#include <hip/hip_bf16.h>
#include <math.h>

#define HID 4096
#define NH 128
#define HD 64
#define DIN 8192      // NH*HD
#define G 8
#define NSTATE 128
#define CS 256
#define GROUP_SIZE 1024
#define CONV_DIM 10240  // DIN + 2*G*NSTATE
#define ZXW 18432       // DIN + CONV_DIM = 72*256 (dt columns handled by fp32 path)
#define BATCH 2
#define SEQ 2048
#define NT (BATCH*SEQ)  // 4096 tokens
#define NC 8            // SEQ/CS
#define DTSK 16         // split-K factor for the fp32 dt GEMM

typedef __attribute__((ext_vector_type(8))) short bf16x8;
typedef __attribute__((ext_vector_type(4))) float f32x4;
typedef __attribute__((ext_vector_type(8))) unsigned short u16x8;
typedef __attribute__((ext_vector_type(4))) unsigned short u16x4;

__device__ __forceinline__ float sigmoidf_(float x){ return 1.f/(1.f+expf(-x)); }
__device__ __forceinline__ float siluf_(float x){ return x*sigmoidf_(x); }
__device__ __forceinline__ float softplusf_(float x){ return (x>20.f)? x : log1pf(expf(x)); }
__device__ __forceinline__ float b2f(unsigned short u){ union{unsigned int i; float f;} x; x.i = ((unsigned int)u)<<16; return x.f; }
__device__ __forceinline__ unsigned short f2b(float f){ __hip_bfloat16 h = __float2bfloat16(f); return *(unsigned short*)&h; }

__device__ __forceinline__ void gload_lds16(const void* g, void* l) {
  __builtin_amdgcn_global_load_lds((const __attribute__((address_space(1))) unsigned int*)g,
                                   (__attribute__((address_space(3))) unsigned int*)l, 16, 0, 0);
}
__device__ __forceinline__ bf16x8 ld8bf(const __hip_bfloat16* p){ return *(const bf16x8*)p; }

__device__ __forceinline__ void cast8(const float* in, __hip_bfloat16* out) {
  const float4* p = (const float4*)in;
  float4 a = p[0], b = p[1];
  union { __hip_bfloat16 h[8]; int4 v; } o;
  o.h[0]=__float2bfloat16(a.x); o.h[1]=__float2bfloat16(a.y);
  o.h[2]=__float2bfloat16(a.z); o.h[3]=__float2bfloat16(a.w);
  o.h[4]=__float2bfloat16(b.x); o.h[5]=__float2bfloat16(b.y);
  o.h[6]=__float2bfloat16(b.z); o.h[7]=__float2bfloat16(b.w);
  *(int4*)out = o.v;
}

// ---------------- all three fp32->bf16 casts in one launch ----------------
__global__ __launch_bounds__(256)
void cast3_kernel(const float* __restrict__ hs, __hip_bfloat16* __restrict__ hs_bf,
                  const float* __restrict__ w_in, __hip_bfloat16* __restrict__ w_in_bf,
                  const float* __restrict__ w_out, __hip_bfloat16* __restrict__ w_out_bf) {
  const size_t n0 = (size_t)NT*HID/8;          // hs
  const size_t n1 = (size_t)ZXW*HID/8;         // in_proj (first ZXW rows)
  const size_t n2 = (size_t)HID*DIN/8;         // out_proj
  const size_t ntot = n0 + n1 + n2;
  size_t i = (size_t)blockIdx.x * 256 + threadIdx.x;
  size_t stride = (size_t)gridDim.x * 256;
  for (; i < ntot; i += stride) {
    if (i < n0)            cast8(hs   + i*8,        hs_bf   + i*8);
    else if (i < n0 + n1)  cast8(w_in + (i-n0)*8,   w_in_bf + (i-n0)*8);
    else                   cast8(w_out+ (i-n0-n1)*8, w_out_bf+ (i-n0-n1)*8);
  }
}

// ---------------- 256x256 bf16 MFMA GEMM, BK=64, 1 barrier + 1 vmcnt per K-tile ----------------
// C[M][N] = A[M][K] * B[N][K]^T. 512 threads = 8 waves (2M x 4N), per-wave 128x64.
// 2 LDS buffers of [256][64] bf16 per operand (128 KiB). Stage tile t+1 at top of iter t;
// vmcnt(0) at iter-top drains tile t's loads issued a FULL iteration (~600 cyc) earlier -> cheap.
// 64 MFMA per barrier (vs 32 per 4 barriers in prior rev). Frag reads are plain C++ loads:
// the compiler emits fine-grained lgkmcnt and pipelines reads into the MFMA clusters (m97 behavior).
// Swizzle: LDS granule (r,g) holds global granule g^(r&7) of row r (128B rows -> 8 granule
// positions; 16-row frag read covers all 8 twice => 2-way, free). ks1 offset = ks0 ^ 32.
// WAR audit: STAGE(t+1) overwrites the buffer read in iter t-1; those reads completed (compiler
// lgkm before their MFMA uses) before that wave reached iter-t's barrier, which precedes the STAGE.
template<bool OUT_BF16>
__global__ __launch_bounds__(512)
void gemm_bf16_256(const __hip_bfloat16* __restrict__ A, const __hip_bfloat16* __restrict__ B,
                   void* __restrict__ Cout, int M, int N, int K) {
  const int nMt = M >> 8, nNt = N >> 8;
  const int nwg = nMt * nNt;
  const int cpx = nwg >> 3;
  const int lin = blockIdx.x;
  const int swz = (lin & 7) * cpx + (lin >> 3);   // XCD-chunked (nwg%8==0)
  const int mt = swz % nMt, ntile = swz / nMt;    // M fastest -> B panel L2-hot
  const int rowBase = mt << 8;
  const int colBase = ntile << 8;

  __shared__ short As[2][16384];   // 2 x 32KB
  __shared__ short Bs[2][16384];

  const int tid = threadIdx.x;
  const int lane = tid & 63, wid = tid >> 6;
  const int wr = wid >> 2, wc = wid & 3;          // 2M x 4N wave grid
  const int l15 = lane & 15, l4 = lane >> 4;

  // staging: load i (i=0..3 per operand) covers granules gidx = i*512 + tid;
  // row = i*64 + (tid>>3), dest granule = tid&7, source granule = (tid&7) ^ (row&7).
  const int rB = tid >> 3;                        // 0..63
  const int cg = (tid & 7) ^ (rB & 7);
  const size_t K64 = (size_t)64 * K;
  const __hip_bfloat16* gA = A + (size_t)(rowBase + rB)*K + cg*8;
  const __hip_bfloat16* gB = B + (size_t)(colBase + rB)*K + cg*8;
  const int lb = wid * 512;                       // shorts; + i*4096 per load

#define STAGE(q, kt) do { \
    gload_lds16(gA + (size_t)(kt)*64,          (void*)&As[q][lb]); \
    gload_lds16(gA + (size_t)(kt)*64 + K64,    (void*)&As[q][4096 + lb]); \
    gload_lds16(gA + (size_t)(kt)*64 + 2*K64,  (void*)&As[q][8192 + lb]); \
    gload_lds16(gA + (size_t)(kt)*64 + 3*K64,  (void*)&As[q][12288 + lb]); \
    gload_lds16(gB + (size_t)(kt)*64,          (void*)&Bs[q][lb]); \
    gload_lds16(gB + (size_t)(kt)*64 + K64,    (void*)&Bs[q][4096 + lb]); \
    gload_lds16(gB + (size_t)(kt)*64 + 2*K64,  (void*)&Bs[q][8192 + lb]); \
    gload_lds16(gB + (size_t)(kt)*64 + 3*K64,  (void*)&Bs[q][12288 + lb]); \
  } while(0)

  // swizzled ds_read element offsets (shorts), ks=0; ks=1 is ^32.
  int aoff[8], boff[4];
  #pragma unroll
  for (int m=0;m<8;++m){ int r = wr*128 + m*16 + l15; aoff[m] = r*64 + ((l4 ^ (r&7))*8); }
  #pragma unroll
  for (int n=0;n<4;++n){ int r = wc*64  + n*16 + l15; boff[n] = r*64 + ((l4 ^ (r&7))*8); }

  f32x4 acc[8][4] = {};
  const int NKT = K >> 6;

  STAGE(0, 0);

  for (int t = 0; t < NKT; ++t) {
    asm volatile("s_waitcnt vmcnt(0)" ::: "memory");   // tile t ready (issued 1 iter ago)
    __builtin_amdgcn_s_barrier();
    if (t + 1 < NKT) STAGE((t+1)&1, t+1);
    const short* ab = &As[t&1][0];
    const short* bb = &Bs[t&1][0];
    bf16x8 a[8], b[4];
    // ---- k-half 0 ----
    #pragma unroll
    for (int m=0;m<8;++m) a[m] = *(const bf16x8*)&ab[aoff[m]];
    #pragma unroll
    for (int n=0;n<4;++n) b[n] = *(const bf16x8*)&bb[boff[n]];
    __builtin_amdgcn_s_setprio(1);
    #pragma unroll
    for (int m=0;m<8;++m)
      #pragma unroll
      for (int n=0;n<4;++n)
        acc[m][n] = __builtin_amdgcn_mfma_f32_16x16x32_bf16(a[m], b[n], acc[m][n], 0, 0, 0);
    __builtin_amdgcn_s_setprio(0);
    // ---- k-half 1 ----
    #pragma unroll
    for (int m=0;m<8;++m) a[m] = *(const bf16x8*)&ab[aoff[m] ^ 32];
    #pragma unroll
    for (int n=0;n<4;++n) b[n] = *(const bf16x8*)&bb[boff[n] ^ 32];
    __builtin_amdgcn_s_setprio(1);
    #pragma unroll
    for (int m=0;m<8;++m)
      #pragma unroll
      for (int n=0;n<4;++n)
        acc[m][n] = __builtin_amdgcn_mfma_f32_16x16x32_bf16(a[m], b[n], acc[m][n], 0, 0, 0);
    __builtin_amdgcn_s_setprio(0);
  }
#undef STAGE

  #pragma unroll
  for (int m=0;m<8;++m) {
    int row0 = rowBase + wr*128 + m*16 + l4*4;
    #pragma unroll
    for (int n=0;n<4;++n) {
      int col = colBase + wc*64 + n*16 + l15;
      #pragma unroll
      for (int j=0;j<4;++j) {
        if (OUT_BF16)
          ((__hip_bfloat16*)Cout)[(size_t)(row0+j)*N + col] = __float2bfloat16(acc[m][n][j]);
        else
          ((float*)Cout)[(size_t)(row0+j)*N + col] = acc[m][n][j];
      }
    }
  }
}

// ---------------- fp32 dt GEMM, split-K: partial[sk][NT][NH] ----------------
__global__ __launch_bounds__(256)
void dt_gemm_splitk(const float* __restrict__ A, const float* __restrict__ B,
                    float* __restrict__ partial) {
  __shared__ float As[16][132];
  __shared__ float Bs[16][132];
  const int tid = threadIdx.x;
  const int tx = tid & 15, ty = tid >> 4;
  const int rowBase = blockIdx.y * 128;
  const int k0 = blockIdx.x * (HID/DTSK);
  float acc[8][8] = {};
  for (int kt = k0; kt < k0 + HID/DTSK; kt += 16) {
    for (int e = tid; e < 128*16; e += 256) {
      int r = e >> 4, c = e & 15;
      As[c][r] = A[(size_t)(rowBase + r) * HID + kt + c];
      Bs[c][r] = B[(size_t)r * HID + kt + c];
    }
    __syncthreads();
    #pragma unroll
    for (int kk = 0; kk < 16; ++kk) {
      float a[8], bv[8];
      #pragma unroll
      for (int i = 0; i < 8; ++i) a[i] = As[kk][ty*8+i];
      #pragma unroll
      for (int j = 0; j < 8; ++j) bv[j] = Bs[kk][tx*8+j];
      #pragma unroll
      for (int i = 0; i < 8; ++i)
        #pragma unroll
        for (int j = 0; j < 8; ++j)
          acc[i][j] += a[i]*bv[j];
    }
    __syncthreads();
  }
  float* outp = partial + (size_t)blockIdx.x * NT * NH;
  for (int i = 0; i < 8; ++i) {
    size_t ro = (size_t)(rowBase + ty*8 + i) * NH + tx*8;
    #pragma unroll
    for (int j = 0; j < 8; ++j) outp[ro + j] = acc[i][j];
  }
}

__global__ __launch_bounds__(256)
void dt_reduce_kernel(const float* __restrict__ partial, float* __restrict__ dtb) {
  int idx = blockIdx.x*256 + threadIdx.x;   // NT*NH
  float s = 0.f;
  #pragma unroll
  for (int sk = 0; sk < DTSK; ++sk) s += partial[(size_t)sk*NT*NH + idx];
  dtb[idx] = s;
}

// ---------------- conv + SiLU -> bf16 split outputs (vectorized, 8 ch/thread) ----------------
__global__ __launch_bounds__(256)
void conv_silu_kernel(const __hip_bfloat16* __restrict__ zx, const float* __restrict__ w,
                      const float* __restrict__ bias,
                      __hip_bfloat16* __restrict__ xbf,
                      __hip_bfloat16* __restrict__ Bbf,
                      __hip_bfloat16* __restrict__ Cbf) {
  int idx = blockIdx.x * 256 + threadIdx.x;   // NT*CONV_DIM/8 threads
  int c8 = idx % (CONV_DIM/8);
  int t  = idx / (CONV_DIM/8);
  int c0 = c8 * 8;
  int l = t & (SEQ-1);
  float acc[8];
  *(float4*)&acc[0] = *(const float4*)&bias[c0];
  *(float4*)&acc[4] = *(const float4*)&bias[c0+4];
  float4 wv[8];
  #pragma unroll
  for (int q=0;q<8;++q) wv[q] = *(const float4*)&w[(c0+q)*4];
  #pragma unroll
  for (int k=0;k<4;++k) {
    if (l - 3 + k >= 0) {
      u16x8 v = *(const u16x8*)&zx[(size_t)(t-3+k)*ZXW + DIN + c0];
      #pragma unroll
      for (int q=0;q<8;++q) acc[q] += b2f(v[q]) * ((const float*)&wv[q])[k];
    }
  }
  u16x8 o;
  #pragma unroll
  for (int q=0;q<8;++q) o[q] = f2b(siluf_(acc[q]));
  if (c0 < DIN) *(u16x8*)&xbf[(size_t)t*DIN + c0] = o;
  else if (c0 < DIN + G*NSTATE) *(u16x8*)&Bbf[(size_t)t*(G*NSTATE) + (c0 - DIN)] = o;
  else *(u16x8*)&Cbf[(size_t)t*(G*NSTATE) + (c0 - DIN - G*NSTATE)] = o;
}

// ---------------- dt softplus + per-chunk cumsum ----------------
__global__ __launch_bounds__(256)
void dt_scan_kernel(float* __restrict__ dtbuf, const float* __restrict__ dt_bias,
                    const float* __restrict__ A_log, float* __restrict__ Acs) {
  int bid = blockIdx.x;       // (b*NH + h)*NC + c
  int c = bid % NC;
  int h = (bid / NC) % NH;
  int b = bid / (NC*NH);
  int k = threadIdx.x;
  int t = b*SEQ + c*CS + k;
  float raw = dtbuf[(size_t)t*NH + h] + dt_bias[h];
  float dtv = softplusf_(raw);
  dtbuf[(size_t)t*NH + h] = dtv;
  float adt = -expf(A_log[h]) * dtv;
  __shared__ float s[CS];
  s[k] = adt;
  __syncthreads();
  for (int off = 1; off < CS; off <<= 1) {
    float v = (k >= off) ? s[k-off] : 0.f;
    __syncthreads();
    s[k] += v;
    __syncthreads();
  }
  Acs[((size_t)(b*NH + h)*NC + c)*CS + k] = s[k];
}

// ---------------- x transpose + dt scaling ----------------
__global__ __launch_bounds__(256)
void prep_xt_kernel(const __hip_bfloat16* __restrict__ xbf, const float* __restrict__ dt_sp,
                    const float* __restrict__ Acs,
                    __hip_bfloat16* __restrict__ xsT, __hip_bfloat16* __restrict__ xwT) {
  int tt = blockIdx.x;   // t-tile of 64
  int h  = blockIdx.y;   // one head = 64 channels
  int t0 = tt*64;
  int b = t0 >> 11, cc = (t0 >> 8) & 7, k0 = t0 & 255;
  __shared__ unsigned short T[64][72];
  __shared__ float dts[64], ews[64];
  int tid = threadIdx.x;
  if (tid < 64) {
    int t = t0 + tid;
    dts[tid] = dt_sp[(size_t)t*NH + h];
    const float* acs = Acs + ((size_t)(b*NH+h)*NC + cc)*CS;
    ews[tid] = __expf(acs[CS-1] - acs[k0 + tid]);
  }
  #pragma unroll
  for (int it = 0; it < 2; ++it) {
    int r = tid >> 2;
    int c8 = (tid & 3) + it*4;
    u16x8 v = *(const u16x8*)&xbf[(size_t)(t0+r)*DIN + h*64 + c8*8];
    #pragma unroll
    for (int q=0;q<8;++q) T[c8*8+q][r] = v[q];
  }
  __syncthreads();
  #pragma unroll
  for (int it = 0; it < 2; ++it) {
    int ch = tid >> 2;
    int tc = (tid & 3) + it*4;
    u16x8 v = *(const u16x8*)&T[ch][tc*8];
    u16x8 a, wv;
    #pragma unroll
    for (int q=0;q<8;++q) {
      float f = b2f(v[q]);
      float fs = f * dts[tc*8+q];
      a[q]  = f2b(fs);
      wv[q] = f2b(fs * ews[tc*8+q]);
    }
    *(u16x8*)&xsT[(size_t)(h*64+ch)*NT + t0 + tc*8] = a;
    *(u16x8*)&xwT[(size_t)(h*64+ch)*NT + t0 + tc*8] = wv;
  }
}

// ---------------- generic 64x64 bf16 transpose (B -> BT) ----------------
__global__ __launch_bounds__(256)
void transpose_bf16_kernel(const __hip_bfloat16* __restrict__ src, __hip_bfloat16* __restrict__ dst, int S) {
  int tt = blockIdx.x;
  int ct = blockIdx.y;
  int t0 = tt*64, c0 = ct*64;
  __shared__ unsigned short T[64][72];
  int tid = threadIdx.x;
  #pragma unroll
  for (int it = 0; it < 2; ++it) {
    int r = tid >> 2;
    int c8 = (tid & 3) + it*4;
    u16x8 v = *(const u16x8*)&src[(size_t)(t0+r)*S + c0 + c8*8];
    #pragma unroll
    for (int q=0;q<8;++q) T[c8*8+q][r] = v[q];
  }
  __syncthreads();
  #pragma unroll
  for (int it = 0; it < 2; ++it) {
    int ch = tid >> 2;
    int tc = (tid & 3) + it*4;
    u16x8 v = *(const u16x8*)&T[ch][tc*8];
    *(u16x8*)&dst[(size_t)(c0+ch)*NT + t0 + tc*8] = v;
  }
}

// ---------------- chunk states via MFMA ----------------
__global__ __launch_bounds__(256)
void chunk_states_mfma(const __hip_bfloat16* __restrict__ xwT, const __hip_bfloat16* __restrict__ BT,
                       float* __restrict__ states) {
  int h = blockIdx.x, bc = blockIdx.y;
  int g = h >> 4;
  int b = bc >> 3, c = bc & 7;
  int tbase = b*SEQ + c*CS;
  int tid = threadIdx.x, lane = tid & 63, w = tid >> 6;
  int l15 = lane & 15, l4 = lane >> 4;
  int n0 = w*32;
  const __hip_bfloat16* xp = xwT + (size_t)(h*64 + l15)*NT + tbase + l4*8;
  const __hip_bfloat16* bp = BT + (size_t)(g*128 + n0 + l15)*NT + tbase + l4*8;
  f32x4 acc[4][2] = {};
  for (int kc = 0; kc < 8; ++kc) {
    bf16x8 xf[4], bf2[2];
    #pragma unroll
    for (int tm=0;tm<4;++tm) xf[tm] = ld8bf(xp + (size_t)(tm*16)*NT + kc*32);
    #pragma unroll
    for (int tn=0;tn<2;++tn) bf2[tn] = ld8bf(bp + (size_t)(tn*16)*NT + kc*32);
    #pragma unroll
    for (int tm=0;tm<4;++tm)
      #pragma unroll
      for (int tn=0;tn<2;++tn)
        acc[tm][tn] = __builtin_amdgcn_mfma_f32_16x16x32_bf16(xf[tm], bf2[tn], acc[tm][tn], 0, 0, 0);
  }
  float* out = states + ((size_t)bc*NH + h)*(HD*NSTATE);
  #pragma unroll
  for (int tm=0;tm<4;++tm)
    #pragma unroll
    for (int tn=0;tn<2;++tn)
      #pragma unroll
      for (int q=0;q<4;++q)
        out[(size_t)(tm*16 + l4*4 + q)*NSTATE + n0 + tn*16 + l15] = acc[tm][tn][q];
}

// ---------------- inter-chunk recurrence ----------------
__global__ void state_recurrence_kernel(const float* __restrict__ states, const float* __restrict__ Acs,
                                        __hip_bfloat16* __restrict__ states_bf) {
  int idx = blockIdx.x*256 + threadIdx.x;  // BATCH*NH*8192
  int dn = idx & 8191;
  int h = (idx >> 13) & 127;
  int b = idx >> 20;
  float S = 0.f;
  for (int c = 0; c < NC; ++c) {
    size_t off = ((size_t)(b*NC + c)*NH + h)*8192 + dn;
    float v = states[off];
    states_bf[off] = __float2bfloat16(S);
    float decay = expf(Acs[((size_t)(b*NH+h)*NC + c)*CS + CS-1]);
    S = S*decay + v;
  }
}

// ---------------- Y via MFMA (wave-causal: wave w only needs j-blocks jb<=w) ----------------
__global__ __launch_bounds__(256)
void y_mfma_kernel(const __hip_bfloat16* __restrict__ zx,
                   const __hip_bfloat16* __restrict__ Cn,
                   const __hip_bfloat16* __restrict__ Bn,
                   const __hip_bfloat16* __restrict__ xsT,
                   const __hip_bfloat16* __restrict__ Sbf,
                   const float* __restrict__ dt_sp,
                   const float* __restrict__ Acs,
                   const float* __restrict__ Dp,
                   __hip_bfloat16* __restrict__ ybf) {
  int h = blockIdx.x;
  int bc = blockIdx.y;
  int c = bc & 7, b = bc >> 3;
  int g = h >> 4;
  int tbase = b*SEQ + c*CS;
  int tid = threadIdx.x, lane = tid & 63, w = tid >> 6;
  int l15 = lane & 15, l4 = lane >> 4;
  int i0 = w*64;
  __shared__ float acs_s[CS];
  __shared__ unsigned short P[4][64][72];
  acs_s[tid] = Acs[((size_t)(b*NH+h)*NC + c)*CS + tid];
  __syncthreads();

  float acs_i[4], rd[4];
  float Dh = Dp[h];
  #pragma unroll
  for (int ti=0;ti<4;++ti) {
    int ig = i0 + ti*16 + l15;
    acs_i[ti] = acs_s[ig];
    rd[ti] = Dh / dt_sp[(size_t)(tbase+ig)*NH + h];
  }
  const __hip_bfloat16* Cbase = Cn + (size_t)tbase*1024 + g*128;
  const __hip_bfloat16* Bbase = Bn + (size_t)tbase*1024 + g*128;
  const __hip_bfloat16* xbase = xsT + (size_t)(h*64 + l15)*NT + tbase;

  f32x4 accY[4][4] = {};
  // wave-causal: j-blocks jb>w are entirely above the diagonal (masked to 0) -> skip.
  for (int jb = 0; jb <= w; ++jb) {
    int j0 = jb*64;
    f32x4 sacc[4][4] = {};
    for (int kc = 0; kc < 4; ++kc) {
      bf16x8 bfr[4], cfr[4];
      #pragma unroll
      for (int tj=0;tj<4;++tj) bfr[tj] = ld8bf(Bbase + (size_t)(j0 + tj*16 + l15)*1024 + kc*32 + l4*8);
      #pragma unroll
      for (int ti=0;ti<4;++ti) cfr[ti] = ld8bf(Cbase + (size_t)(i0 + ti*16 + l15)*1024 + kc*32 + l4*8);
      #pragma unroll
      for (int tj=0;tj<4;++tj)
        #pragma unroll
        for (int ti=0;ti<4;++ti)
          sacc[tj][ti] = __builtin_amdgcn_mfma_f32_16x16x32_bf16(bfr[tj], cfr[ti], sacc[tj][ti], 0, 0, 0);
    }
    #pragma unroll
    for (int tj=0;tj<4;++tj)
      #pragma unroll
      for (int ti=0;ti<4;++ti) {
        int ig = i0 + ti*16 + l15;
        float ai = acs_i[ti];
        u16x4 pk;
        #pragma unroll
        for (int q=0;q<4;++q) {
          int jg = j0 + tj*16 + l4*4 + q;
          float v = (jg <= ig) ? sacc[tj][ti][q] * __expf(ai - acs_s[jg]) : 0.f;
          if (jg == ig) v += rd[ti];
          pk[q] = f2b(v);
        }
        *(u16x4*)&P[w][ti*16 + l15][tj*16 + l4*4] = pk;
      }
    #pragma unroll
    for (int kc2 = 0; kc2 < 2; ++kc2) {
      bf16x8 xf[4], pf[4];
      #pragma unroll
      for (int tm=0;tm<4;++tm) xf[tm] = ld8bf(xbase + (size_t)(tm*16)*NT + j0 + kc2*32 + l4*8);
      #pragma unroll
      for (int ti=0;ti<4;++ti) pf[ti] = *(const bf16x8*)&P[w][ti*16 + l15][kc2*32 + l4*8];
      #pragma unroll
      for (int tm=0;tm<4;++tm)
        #pragma unroll
        for (int ti=0;ti<4;++ti)
          accY[tm][ti] = __builtin_amdgcn_mfma_f32_16x16x32_bf16(xf[tm], pf[ti], accY[tm][ti], 0, 0, 0);
    }
  }
  const __hip_bfloat16* Sb = Sbf + ((size_t)bc*NH + h)*(HD*NSTATE);
  f32x4 oacc[4][4] = {};
  for (int kc = 0; kc < 4; ++kc) {
    bf16x8 sf[4], cfr[4];
    #pragma unroll
    for (int tm=0;tm<4;++tm) sf[tm] = ld8bf(Sb + (size_t)(tm*16 + l15)*NSTATE + kc*32 + l4*8);
    #pragma unroll
    for (int ti=0;ti<4;++ti) cfr[ti] = ld8bf(Cbase + (size_t)(i0 + ti*16 + l15)*1024 + kc*32 + l4*8);
    #pragma unroll
    for (int tm=0;tm<4;++tm)
      #pragma unroll
      for (int ti=0;ti<4;++ti)
        oacc[tm][ti] = __builtin_amdgcn_mfma_f32_16x16x32_bf16(sf[tm], cfr[ti], oacc[tm][ti], 0, 0, 0);
  }
  #pragma unroll
  for (int ti=0;ti<4;++ti) {
    int ig = i0 + ti*16 + l15;
    int t = tbase + ig;
    float sd = __expf(acs_i[ti]);
    #pragma unroll
    for (int tm=0;tm<4;++tm) {
      int ch0 = h*64 + tm*16 + l4*4;
      u16x4 gv = *(const u16x4*)&zx[(size_t)t*ZXW + ch0];
      u16x4 out;
      #pragma unroll
      for (int q=0;q<4;++q) {
        float yv = accY[tm][ti][q] + sd * oacc[tm][ti][q];
        yv *= siluf_(b2f(gv[q]));
        out[q] = f2b(yv);
      }
      *(u16x4*)&ybf[(size_t)t*DIN + ch0] = out;
    }
  }
}

// ---------------- RMS groupnorm, bf16 in-place ----------------
__global__ __launch_bounds__(256)
void groupnorm_bf16_kernel(unsigned short* __restrict__ y, const float* __restrict__ norm_w) {
  int bid = blockIdx.x;
  int g = bid % G;
  int t = bid / G;
  unsigned short* yp = y + (size_t)t*DIN + g*GROUP_SIZE;
  int tid = threadIdx.x;
  u16x4 v = *(const u16x4*)&yp[tid*4];
  float f[4]; float ss = 0.f;
  #pragma unroll
  for (int j=0;j<4;++j) { f[j] = b2f(v[j]); ss += f[j]*f[j]; }
  #pragma unroll
  for (int off = 32; off > 0; off >>= 1) ss += __shfl_xor(ss, off);
  __shared__ float wsum[4];
  int wave = tid >> 6;
  if ((tid & 63) == 0) wsum[wave] = ss;
  __syncthreads();
  float tot = wsum[0]+wsum[1]+wsum[2]+wsum[3];
  float rs = rsqrtf(tot/(float)GROUP_SIZE + 1e-5f);
  const float* nw = norm_w + g*GROUP_SIZE + tid*4;
  u16x4 o;
  #pragma unroll
  for (int j=0;j<4;++j) o[j] = f2b(f[j] * rs * nw[j]);
  *(u16x4*)&yp[tid*4] = o;
}

extern "C" void kernel_launch(void* const* d_in, const int* in_sizes, int n_in,
                              void* d_out, int out_size, void* d_ws, size_t ws_size,
                              hipStream_t stream) {
  const float* hs        = (const float*)d_in[0];
  const float* in_proj_w = (const float*)d_in[1];
  const float* conv_w    = (const float*)d_in[2];
  const float* conv_b    = (const float*)d_in[3];
  const float* dt_bias   = (const float*)d_in[4];
  const float* A_log     = (const float*)d_in[5];
  const float* Dp        = (const float*)d_in[6];
  const float* norm_w    = (const float*)d_in[7];
  const float* out_proj_w= (const float*)d_in[8];
  float* outp = (float*)d_out;

  char* ws = (char*)d_ws;
  __hip_bfloat16* zx_bf = (__hip_bfloat16*)ws;                      // NT*ZXW*2 = 150,994,944
  char* p = ws + (size_t)NT*ZXW*2;
  __hip_bfloat16* x_bf  = (__hip_bfloat16*)p; p += (size_t)NT*DIN*2;          // 67,108,864
  __hip_bfloat16* B_bf  = (__hip_bfloat16*)p; p += (size_t)NT*G*NSTATE*2;     // 8,388,608
  __hip_bfloat16* C_bf  = (__hip_bfloat16*)p; p += (size_t)NT*G*NSTATE*2;     // 8,388,608
  __hip_bfloat16* BT    = (__hip_bfloat16*)p; p += (size_t)NT*G*NSTATE*2;     // 8,388,608
  float* states = (float*)p;  p += (size_t)BATCH*NC*NH*HD*NSTATE*4;           // 67,108,864
  __hip_bfloat16* y_bf  = (__hip_bfloat16*)p; p += (size_t)NT*DIN*2;          // 67,108,864
  float* dtb    = (float*)p;  p += (size_t)NT*NH*4;                            // 2,097,152
  float* Acs    = (float*)p;  p += (size_t)BATCH*NH*NC*CS*4;                   // 2,097,152
  // dt split-K partials alias y_bf (dead until y_mfma): DTSK*NT*NH*4 = 33.5 MB
  float* dt_part = (float*)y_bf;
  // overlapped region F
  char* F = p;
  __hip_bfloat16* w_in_bf   = (__hip_bfloat16*)F;                   // ZXW x HID bf16 (150,994,944)
  __hip_bfloat16* xsT       = (__hip_bfloat16*)F;                   // after in_proj done
  __hip_bfloat16* xwT       = (__hip_bfloat16*)(F + 67108864);
  __hip_bfloat16* hs_bf     = (__hip_bfloat16*)(F + 150994944);     // until in_proj done
  __hip_bfloat16* states_bf = (__hip_bfloat16*)(F + 150994944);     // after recurrence (hs_bf dead)
  char* F2 = F + 150994944 + 33554432;
  __hip_bfloat16* w_out_bf  = (__hip_bfloat16*)F2;                  // 67,108,864

  // dt columns in fp32 (precision-critical), split-K for parallelism
  dt_gemm_splitk<<<dim3(DTSK, NT/128), 256, 0, stream>>>(hs, in_proj_w + (size_t)ZXW*HID, dt_part);
  dt_reduce_kernel<<<(NT*NH)/256, 256, 0, stream>>>(dt_part, dtb);

  // all casts in one launch
  cast3_kernel<<<4096, 256, 0, stream>>>(hs, hs_bf, in_proj_w, w_in_bf, out_proj_w, w_out_bf);

  // in_proj: M=4096, N=ZXW=18432 (72x256 exactly), K=4096 -> 1152 blocks
  gemm_bf16_256<true><<<dim3((NT/256)*(ZXW/256)), 512, 0, stream>>>(
      hs_bf, w_in_bf, zx_bf, NT, ZXW, HID);

  conv_silu_kernel<<<(NT*CONV_DIM/8)/256, 256, 0, stream>>>(zx_bf, conv_w, conv_b, x_bf, B_bf, C_bf);
  dt_scan_kernel<<<BATCH*NH*NC, CS, 0, stream>>>(dtb, dt_bias, A_log, Acs);
  prep_xt_kernel<<<dim3(NT/64, NH), 256, 0, stream>>>(x_bf, dtb, Acs, xsT, xwT);
  transpose_bf16_kernel<<<dim3(NT/64, (G*NSTATE)/64), 256, 0, stream>>>(B_bf, BT, G*NSTATE);
  chunk_states_mfma<<<dim3(NH, BATCH*NC), 256, 0, stream>>>(xwT, BT, states);
  state_recurrence_kernel<<<(BATCH*NH*HD*NSTATE)/256, 256, 0, stream>>>(states, Acs, states_bf);
  y_mfma_kernel<<<dim3(NH, BATCH*NC), 256, 0, stream>>>(zx_bf, C_bf, B_bf, xsT, states_bf, dtb, Acs, Dp, y_bf);
  groupnorm_bf16_kernel<<<NT*G, 256, 0, stream>>>((unsigned short*)y_bf, norm_w);

  // out_proj: M=4096, N=4096, K=8192 -> 256 blocks
  gemm_bf16_256<false><<<dim3((NT/256)*(HID/256)), 512, 0, stream>>>(
      y_bf, w_out_bf, outp, NT, HID, DIN);
}

// Round 12
// 1815.602 us; speedup vs baseline: 1.0761x; 1.0761x over previous
//
#include <hip/hip_runtime.h>
#include <hip/hip_bf16.h>
#include <math.h>

#define HID 4096
#define NH 128
#define HD 64
#define DIN 8192      // NH*HD
#define G 8
#define NSTATE 128
#define CS 256
#define GROUP_SIZE 1024
#define CONV_DIM 10240  // DIN + 2*G*NSTATE
#define ZXW 18432       // DIN + CONV_DIM = 72*256 (dt columns handled by fp32 path)
#define BATCH 2
#define SEQ 2048
#define NT (BATCH*SEQ)  // 4096 tokens
#define NC 8            // SEQ/CS
#define DTSK 16         // split-K factor for the fp32 dt GEMM

typedef __attribute__((ext_vector_type(8))) short bf16x8;
typedef __attribute__((ext_vector_type(4))) float f32x4;
typedef __attribute__((ext_vector_type(8))) unsigned short u16x8;
typedef __attribute__((ext_vector_type(4))) unsigned short u16x4;

__device__ __forceinline__ float sigmoidf_(float x){ return 1.f/(1.f+expf(-x)); }
__device__ __forceinline__ float siluf_(float x){ return x*sigmoidf_(x); }
__device__ __forceinline__ float softplusf_(float x){ return (x>20.f)? x : log1pf(expf(x)); }
__device__ __forceinline__ float b2f(unsigned short u){ union{unsigned int i; float f;} x; x.i = ((unsigned int)u)<<16; return x.f; }
__device__ __forceinline__ unsigned short f2b(float f){ __hip_bfloat16 h = __float2bfloat16(f); return *(unsigned short*)&h; }

__device__ __forceinline__ void gload_lds16(const void* g, void* l) {
  __builtin_amdgcn_global_load_lds((const __attribute__((address_space(1))) unsigned int*)g,
                                   (__attribute__((address_space(3))) unsigned int*)l, 16, 0, 0);
}
__device__ __forceinline__ bf16x8 ld8bf(const __hip_bfloat16* p){ return *(const bf16x8*)p; }

__device__ __forceinline__ void cast8(const float* in, __hip_bfloat16* out) {
  const float4* p = (const float4*)in;
  float4 a = p[0], b = p[1];
  union { __hip_bfloat16 h[8]; int4 v; } o;
  o.h[0]=__float2bfloat16(a.x); o.h[1]=__float2bfloat16(a.y);
  o.h[2]=__float2bfloat16(a.z); o.h[3]=__float2bfloat16(a.w);
  o.h[4]=__float2bfloat16(b.x); o.h[5]=__float2bfloat16(b.y);
  o.h[6]=__float2bfloat16(b.z); o.h[7]=__float2bfloat16(b.w);
  *(int4*)out = o.v;
}

// ---------------- all three fp32->bf16 casts in one launch ----------------
__global__ __launch_bounds__(256)
void cast3_kernel(const float* __restrict__ hs, __hip_bfloat16* __restrict__ hs_bf,
                  const float* __restrict__ w_in, __hip_bfloat16* __restrict__ w_in_bf,
                  const float* __restrict__ w_out, __hip_bfloat16* __restrict__ w_out_bf) {
  const size_t n0 = (size_t)NT*HID/8;          // hs
  const size_t n1 = (size_t)ZXW*HID/8;         // in_proj (first ZXW rows)
  const size_t n2 = (size_t)HID*DIN/8;         // out_proj
  const size_t ntot = n0 + n1 + n2;
  size_t i = (size_t)blockIdx.x * 256 + threadIdx.x;
  size_t stride = (size_t)gridDim.x * 256;
  for (; i < ntot; i += stride) {
    if (i < n0)            cast8(hs   + i*8,        hs_bf   + i*8);
    else if (i < n0 + n1)  cast8(w_in + (i-n0)*8,   w_in_bf + (i-n0)*8);
    else                   cast8(w_out+ (i-n0-n1)*8, w_out_bf+ (i-n0-n1)*8);
  }
}

// ---------------- 256x256 bf16 MFMA GEMM, 2-phase interleave, counted vmcnt ----------------
// (round-8 version: best measured, MfmaUtil 37%, bank conflicts 0)
template<bool OUT_BF16>
__global__ __launch_bounds__(512)
void gemm_bf16_256(const __hip_bfloat16* __restrict__ A, const __hip_bfloat16* __restrict__ B,
                   void* __restrict__ Cout, int M, int N, int K) {
  const int nMt = M >> 8, nNt = N >> 8;
  const int nwg = nMt * nNt;
  const int cpx = nwg >> 3;
  const int lin = blockIdx.x;
  const int swz = (lin & 7) * cpx + (lin >> 3);   // XCD-chunked (nwg%8==0)
  const int mt = swz % nMt, ntile = swz / nMt;    // M fastest -> B panel L2-hot
  const int rowBase = mt << 8;
  const int colBase = ntile << 8;

  __shared__ short As[4][8192];   // 4 x 16KB
  __shared__ short Bs[4][8192];

  const int tid = threadIdx.x;
  const int lane = tid & 63, wid = tid >> 6;
  const int wr = wid >> 2, wc = wid & 3;          // 2M x 4N wave grid
  const int l15 = lane & 15, l4 = lane >> 4;

  const int r0 = tid >> 2,        c0 = (tid & 3) ^ ((r0 >> 1) & 3);
  const int r1 = (512+tid) >> 2,  c1 = ((512+tid) & 3) ^ ((r1 >> 1) & 3);
  const __hip_bfloat16* gA0 = A + (size_t)(rowBase + r0)*K + c0*8;
  const __hip_bfloat16* gA1 = A + (size_t)(rowBase + r1)*K + c1*8;
  const __hip_bfloat16* gB0 = B + (size_t)(colBase + r0)*K + c0*8;
  const __hip_bfloat16* gB1 = B + (size_t)(colBase + r1)*K + c1*8;
  const int ld0 = wid*512, ld1 = 4096 + wid*512;

#define STAGE_A(q, kt) do { \
    gload_lds16(gA0 + (size_t)(kt)*32, (void*)&As[q][ld0]); \
    gload_lds16(gA1 + (size_t)(kt)*32, (void*)&As[q][ld1]); \
  } while(0)
#define STAGE_B(q, kt) do { \
    gload_lds16(gB0 + (size_t)(kt)*32, (void*)&Bs[q][ld0]); \
    gload_lds16(gB1 + (size_t)(kt)*32, (void*)&Bs[q][ld1]); \
  } while(0)

  int aoff[8], boff[4];
  #pragma unroll
  for (int m=0;m<8;++m){ int r = wr*128 + m*16 + l15; aoff[m] = r*32 + ((l4 ^ ((r>>1)&3))*8); }
  #pragma unroll
  for (int n=0;n<4;++n){ int r = wc*64  + n*16 + l15; boff[n] = r*32 + ((l4 ^ ((r>>1)&3))*8); }

  f32x4 acc[8][4] = {};
  const int NKT = K >> 5;

  STAGE_A(0,0); STAGE_B(0,0);
  STAGE_A(1,1); STAGE_B(1,1);
  STAGE_A(2,2); STAGE_B(2,2);
  asm volatile("s_waitcnt vmcnt(8)" ::: "memory");
  __builtin_amdgcn_s_barrier();

  for (int t = 0; t < NKT; ++t) {
    const short* ab = &As[t&3][0];
    const short* bb = &Bs[t&3][0];
    const int q3 = (t+3)&3;
    bf16x8 a[4], b[4], a2[4];
    // phase A
    #pragma unroll
    for (int m=0;m<4;++m) a[m] = *(const bf16x8*)&ab[aoff[m]];
    #pragma unroll
    for (int n=0;n<4;++n) b[n] = *(const bf16x8*)&bb[boff[n]];
    if (t + 3 < NKT) STAGE_A(q3, t+3);
    __builtin_amdgcn_s_barrier();
    asm volatile("s_waitcnt lgkmcnt(0)" ::: "memory");
    __builtin_amdgcn_sched_barrier(0);
    __builtin_amdgcn_s_setprio(1);
    #pragma unroll
    for (int m=0;m<4;++m)
      #pragma unroll
      for (int n=0;n<4;++n)
        acc[m][n] = __builtin_amdgcn_mfma_f32_16x16x32_bf16(a[m], b[n], acc[m][n], 0, 0, 0);
    __builtin_amdgcn_s_setprio(0);
    __builtin_amdgcn_s_barrier();
    // phase B
    #pragma unroll
    for (int m=0;m<4;++m) a2[m] = *(const bf16x8*)&ab[aoff[m+4]];
    if (t + 3 < NKT) STAGE_B(q3, t+3);
    const int rem = NKT - 1 - t;
    if (rem >= 3)      asm volatile("s_waitcnt vmcnt(8)" ::: "memory");
    else if (rem == 2) asm volatile("s_waitcnt vmcnt(4)" ::: "memory");
    else if (rem == 1) asm volatile("s_waitcnt vmcnt(0)" ::: "memory");
    __builtin_amdgcn_s_barrier();
    asm volatile("s_waitcnt lgkmcnt(0)" ::: "memory");
    __builtin_amdgcn_sched_barrier(0);
    __builtin_amdgcn_s_setprio(1);
    #pragma unroll
    for (int m=0;m<4;++m)
      #pragma unroll
      for (int n=0;n<4;++n)
        acc[m+4][n] = __builtin_amdgcn_mfma_f32_16x16x32_bf16(a2[m], b[n], acc[m+4][n], 0, 0, 0);
    __builtin_amdgcn_s_setprio(0);
    __builtin_amdgcn_s_barrier();
  }
#undef STAGE_A
#undef STAGE_B

  #pragma unroll
  for (int m=0;m<8;++m) {
    int row0 = rowBase + wr*128 + m*16 + l4*4;
    #pragma unroll
    for (int n=0;n<4;++n) {
      int col = colBase + wc*64 + n*16 + l15;
      #pragma unroll
      for (int j=0;j<4;++j) {
        if (OUT_BF16)
          ((__hip_bfloat16*)Cout)[(size_t)(row0+j)*N + col] = __float2bfloat16(acc[m][n][j]);
        else
          ((float*)Cout)[(size_t)(row0+j)*N + col] = acc[m][n][j];
      }
    }
  }
}

// ---------------- fp32 dt GEMM, split-K: partial[sk][NT][NH] ----------------
__global__ __launch_bounds__(256)
void dt_gemm_splitk(const float* __restrict__ A, const float* __restrict__ B,
                    float* __restrict__ partial) {
  __shared__ float As[16][132];
  __shared__ float Bs[16][132];
  const int tid = threadIdx.x;
  const int tx = tid & 15, ty = tid >> 4;
  const int rowBase = blockIdx.y * 128;
  const int k0 = blockIdx.x * (HID/DTSK);
  float acc[8][8] = {};
  for (int kt = k0; kt < k0 + HID/DTSK; kt += 16) {
    for (int e = tid; e < 128*16; e += 256) {
      int r = e >> 4, c = e & 15;
      As[c][r] = A[(size_t)(rowBase + r) * HID + kt + c];
      Bs[c][r] = B[(size_t)r * HID + kt + c];
    }
    __syncthreads();
    #pragma unroll
    for (int kk = 0; kk < 16; ++kk) {
      float a[8], bv[8];
      #pragma unroll
      for (int i = 0; i < 8; ++i) a[i] = As[kk][ty*8+i];
      #pragma unroll
      for (int j = 0; j < 8; ++j) bv[j] = Bs[kk][tx*8+j];
      #pragma unroll
      for (int i = 0; i < 8; ++i)
        #pragma unroll
        for (int j = 0; j < 8; ++j)
          acc[i][j] += a[i]*bv[j];
    }
    __syncthreads();
  }
  float* outp = partial + (size_t)blockIdx.x * NT * NH;
  for (int i = 0; i < 8; ++i) {
    size_t ro = (size_t)(rowBase + ty*8 + i) * NH + tx*8;
    #pragma unroll
    for (int j = 0; j < 8; ++j) outp[ro + j] = acc[i][j];
  }
}

// ---------------- dt: split-K reduce + softplus + per-chunk cumsum (merged) ----------------
__global__ __launch_bounds__(256)
void dt_scan_kernel(const float* __restrict__ partial, const float* __restrict__ dt_bias,
                    const float* __restrict__ A_log, float* __restrict__ dt_sp,
                    float* __restrict__ Acs) {
  int bid = blockIdx.x;       // (b*NH + h)*NC + c
  int c = bid % NC;
  int h = (bid / NC) % NH;
  int b = bid / (NC*NH);
  int k = threadIdx.x;
  int t = b*SEQ + c*CS + k;
  float raw = dt_bias[h];
  #pragma unroll
  for (int sk = 0; sk < DTSK; ++sk) raw += partial[(size_t)sk*NT*NH + (size_t)t*NH + h];
  float dtv = softplusf_(raw);
  dt_sp[(size_t)t*NH + h] = dtv;
  float adt = -expf(A_log[h]) * dtv;
  __shared__ float s[CS];
  s[k] = adt;
  __syncthreads();
  for (int off = 1; off < CS; off <<= 1) {
    float v = (k >= off) ? s[k-off] : 0.f;
    __syncthreads();
    s[k] += v;
    __syncthreads();
  }
  Acs[((size_t)(b*NH + h)*NC + c)*CS + k] = s[k];
}

// ---------------- fused conv+SiLU + transpose + dt scaling ----------------
// grid (NT/64, CONV_DIM/64). x-tiles (ct<128): conv -> LDS transpose -> xsT=(x*dt)^T,
// xwT=(x*dt*exp(alast-acs))^T. B-tiles (128<=ct<144): write Bbf row-major + BT transposed.
// C-tiles (ct>=144): write Cbf row-major only.
__global__ __launch_bounds__(256)
void conv_fused_kernel(const __hip_bfloat16* __restrict__ zx, const float* __restrict__ w,
                       const float* __restrict__ bias,
                       const float* __restrict__ dt_sp, const float* __restrict__ Acs,
                       __hip_bfloat16* __restrict__ xsT, __hip_bfloat16* __restrict__ xwT,
                       __hip_bfloat16* __restrict__ Bbf, __hip_bfloat16* __restrict__ Cbf,
                       __hip_bfloat16* __restrict__ BT) {
  const int tt = blockIdx.x;
  const int ct = blockIdx.y;
  const int t0 = tt*64;
  const int ch0 = ct*64;               // conv-channel base
  const int tid = threadIdx.x;
  __shared__ unsigned short T[64][72];
  __shared__ float dts[64], ews[64];

  const bool isX = (ch0 < DIN);
  const bool isB = (ch0 >= DIN) && (ch0 < DIN + G*NSTATE);

  if (isX && tid < 64) {
    int h = ch0 >> 6;
    int t = t0 + tid;
    dts[tid] = dt_sp[(size_t)t*NH + h];
    int b = t0 >> 11, cc = (t0 >> 8) & 7, k0 = t0 & 255;
    const float* acs = Acs + ((size_t)(b*NH+h)*NC + cc)*CS;
    ews[tid] = __expf(acs[CS-1] - acs[k0 + tid]);
  }

  const int l0 = t0 & (SEQ-1);
  #pragma unroll
  for (int it = 0; it < 2; ++it) {
    int r = tid >> 2;
    int c8 = (tid & 3) + it*4;
    int cb = ch0 + c8*8;
    float acc[8];
    *(float4*)&acc[0] = *(const float4*)&bias[cb];
    *(float4*)&acc[4] = *(const float4*)&bias[cb+4];
    float4 wv[8];
    #pragma unroll
    for (int q=0;q<8;++q) wv[q] = *(const float4*)&w[(cb+q)*4];
    #pragma unroll
    for (int k=0;k<4;++k) {
      if (l0 + r - 3 + k >= 0) {
        u16x8 v = *(const u16x8*)&zx[(size_t)(t0+r-3+k)*ZXW + DIN + cb];
        #pragma unroll
        for (int q=0;q<8;++q) acc[q] += b2f(v[q]) * ((const float*)&wv[q])[k];
      }
    }
    u16x8 o;
    #pragma unroll
    for (int q=0;q<8;++q) o[q] = f2b(siluf_(acc[q]));
    if (isX || isB) {
      #pragma unroll
      for (int q=0;q<8;++q) T[c8*8+q][r] = o[q];
    }
    if (!isX) {
      if (isB) *(u16x8*)&Bbf[(size_t)(t0+r)*(G*NSTATE) + (cb - DIN)] = o;
      else     *(u16x8*)&Cbf[(size_t)(t0+r)*(G*NSTATE) + (cb - DIN - G*NSTATE)] = o;
    }
  }
  if (!isX && !isB) return;          // C-tile blocks exit uniformly (no barrier below)
  __syncthreads();
  #pragma unroll
  for (int it = 0; it < 2; ++it) {
    int ch = tid >> 2;
    int tc = (tid & 3) + it*4;
    u16x8 v = *(const u16x8*)&T[ch][tc*8];
    if (isX) {
      u16x8 a, wv2;
      #pragma unroll
      for (int q=0;q<8;++q) {
        float f = b2f(v[q]);
        float fs = f * dts[tc*8+q];
        a[q]   = f2b(fs);
        wv2[q] = f2b(fs * ews[tc*8+q]);
      }
      *(u16x8*)&xsT[(size_t)(ch0+ch)*NT + t0 + tc*8] = a;
      *(u16x8*)&xwT[(size_t)(ch0+ch)*NT + t0 + tc*8] = wv2;
    } else {
      *(u16x8*)&BT[(size_t)(ch0 - DIN + ch)*NT + t0 + tc*8] = v;
    }
  }
}

// ---------------- chunk states via MFMA ----------------
__global__ __launch_bounds__(256)
void chunk_states_mfma(const __hip_bfloat16* __restrict__ xwT, const __hip_bfloat16* __restrict__ BT,
                       float* __restrict__ states) {
  int h = blockIdx.x, bc = blockIdx.y;
  int g = h >> 4;
  int b = bc >> 3, c = bc & 7;
  int tbase = b*SEQ + c*CS;
  int tid = threadIdx.x, lane = tid & 63, w = tid >> 6;
  int l15 = lane & 15, l4 = lane >> 4;
  int n0 = w*32;
  const __hip_bfloat16* xp = xwT + (size_t)(h*64 + l15)*NT + tbase + l4*8;
  const __hip_bfloat16* bp = BT + (size_t)(g*128 + n0 + l15)*NT + tbase + l4*8;
  f32x4 acc[4][2] = {};
  for (int kc = 0; kc < 8; ++kc) {
    bf16x8 xf[4], bf2[2];
    #pragma unroll
    for (int tm=0;tm<4;++tm) xf[tm] = ld8bf(xp + (size_t)(tm*16)*NT + kc*32);
    #pragma unroll
    for (int tn=0;tn<2;++tn) bf2[tn] = ld8bf(bp + (size_t)(tn*16)*NT + kc*32);
    #pragma unroll
    for (int tm=0;tm<4;++tm)
      #pragma unroll
      for (int tn=0;tn<2;++tn)
        acc[tm][tn] = __builtin_amdgcn_mfma_f32_16x16x32_bf16(xf[tm], bf2[tn], acc[tm][tn], 0, 0, 0);
  }
  float* out = states + ((size_t)bc*NH + h)*(HD*NSTATE);
  #pragma unroll
  for (int tm=0;tm<4;++tm)
    #pragma unroll
    for (int tn=0;tn<2;++tn)
      #pragma unroll
      for (int q=0;q<4;++q)
        out[(size_t)(tm*16 + l4*4 + q)*NSTATE + n0 + tn*16 + l15] = acc[tm][tn][q];
}

// ---------------- inter-chunk recurrence ----------------
__global__ void state_recurrence_kernel(const float* __restrict__ states, const float* __restrict__ Acs,
                                        __hip_bfloat16* __restrict__ states_bf) {
  int idx = blockIdx.x*256 + threadIdx.x;  // BATCH*NH*8192
  int dn = idx & 8191;
  int h = (idx >> 13) & 127;
  int b = idx >> 20;
  float S = 0.f;
  for (int c = 0; c < NC; ++c) {
    size_t off = ((size_t)(b*NC + c)*NH + h)*8192 + dn;
    float v = states[off];
    states_bf[off] = __float2bfloat16(S);
    float decay = expf(Acs[((size_t)(b*NH+h)*NC + c)*CS + CS-1]);
    S = S*decay + v;
  }
}

// ---------------- Y via MFMA (wave-causal) ----------------
__global__ __launch_bounds__(256)
void y_mfma_kernel(const __hip_bfloat16* __restrict__ zx,
                   const __hip_bfloat16* __restrict__ Cn,
                   const __hip_bfloat16* __restrict__ Bn,
                   const __hip_bfloat16* __restrict__ xsT,
                   const __hip_bfloat16* __restrict__ Sbf,
                   const float* __restrict__ dt_sp,
                   const float* __restrict__ Acs,
                   const float* __restrict__ Dp,
                   __hip_bfloat16* __restrict__ ybf) {
  int h = blockIdx.x;
  int bc = blockIdx.y;
  int c = bc & 7, b = bc >> 3;
  int g = h >> 4;
  int tbase = b*SEQ + c*CS;
  int tid = threadIdx.x, lane = tid & 63, w = tid >> 6;
  int l15 = lane & 15, l4 = lane >> 4;
  int i0 = w*64;
  __shared__ float acs_s[CS];
  __shared__ unsigned short P[4][64][72];
  acs_s[tid] = Acs[((size_t)(b*NH+h)*NC + c)*CS + tid];
  __syncthreads();

  float acs_i[4], rd[4];
  float Dh = Dp[h];
  #pragma unroll
  for (int ti=0;ti<4;++ti) {
    int ig = i0 + ti*16 + l15;
    acs_i[ti] = acs_s[ig];
    rd[ti] = Dh / dt_sp[(size_t)(tbase+ig)*NH + h];
  }
  const __hip_bfloat16* Cbase = Cn + (size_t)tbase*1024 + g*128;
  const __hip_bfloat16* Bbase = Bn + (size_t)tbase*1024 + g*128;
  const __hip_bfloat16* xbase = xsT + (size_t)(h*64 + l15)*NT + tbase;

  f32x4 accY[4][4] = {};
  for (int jb = 0; jb <= w; ++jb) {
    int j0 = jb*64;
    f32x4 sacc[4][4] = {};
    for (int kc = 0; kc < 4; ++kc) {
      bf16x8 bfr[4], cfr[4];
      #pragma unroll
      for (int tj=0;tj<4;++tj) bfr[tj] = ld8bf(Bbase + (size_t)(j0 + tj*16 + l15)*1024 + kc*32 + l4*8);
      #pragma unroll
      for (int ti=0;ti<4;++ti) cfr[ti] = ld8bf(Cbase + (size_t)(i0 + ti*16 + l15)*1024 + kc*32 + l4*8);
      #pragma unroll
      for (int tj=0;tj<4;++tj)
        #pragma unroll
        for (int ti=0;ti<4;++ti)
          sacc[tj][ti] = __builtin_amdgcn_mfma_f32_16x16x32_bf16(bfr[tj], cfr[ti], sacc[tj][ti], 0, 0, 0);
    }
    #pragma unroll
    for (int tj=0;tj<4;++tj)
      #pragma unroll
      for (int ti=0;ti<4;++ti) {
        int ig = i0 + ti*16 + l15;
        float ai = acs_i[ti];
        u16x4 pk;
        #pragma unroll
        for (int q=0;q<4;++q) {
          int jg = j0 + tj*16 + l4*4 + q;
          float v = (jg <= ig) ? sacc[tj][ti][q] * __expf(ai - acs_s[jg]) : 0.f;
          if (jg == ig) v += rd[ti];
          pk[q] = f2b(v);
        }
        *(u16x4*)&P[w][ti*16 + l15][tj*16 + l4*4] = pk;
      }
    #pragma unroll
    for (int kc2 = 0; kc2 < 2; ++kc2) {
      bf16x8 xf[4], pf[4];
      #pragma unroll
      for (int tm=0;tm<4;++tm) xf[tm] = ld8bf(xbase + (size_t)(tm*16)*NT + j0 + kc2*32 + l4*8);
      #pragma unroll
      for (int ti=0;ti<4;++ti) pf[ti] = *(const bf16x8*)&P[w][ti*16 + l15][kc2*32 + l4*8];
      #pragma unroll
      for (int tm=0;tm<4;++tm)
        #pragma unroll
        for (int ti=0;ti<4;++ti)
          accY[tm][ti] = __builtin_amdgcn_mfma_f32_16x16x32_bf16(xf[tm], pf[ti], accY[tm][ti], 0, 0, 0);
    }
  }
  const __hip_bfloat16* Sb = Sbf + ((size_t)bc*NH + h)*(HD*NSTATE);
  f32x4 oacc[4][4] = {};
  for (int kc = 0; kc < 4; ++kc) {
    bf16x8 sf[4], cfr[4];
    #pragma unroll
    for (int tm=0;tm<4;++tm) sf[tm] = ld8bf(Sb + (size_t)(tm*16 + l15)*NSTATE + kc*32 + l4*8);
    #pragma unroll
    for (int ti=0;ti<4;++ti) cfr[ti] = ld8bf(Cbase + (size_t)(i0 + ti*16 + l15)*1024 + kc*32 + l4*8);
    #pragma unroll
    for (int tm=0;tm<4;++tm)
      #pragma unroll
      for (int ti=0;ti<4;++ti)
        oacc[tm][ti] = __builtin_amdgcn_mfma_f32_16x16x32_bf16(sf[tm], cfr[ti], oacc[tm][ti], 0, 0, 0);
  }
  #pragma unroll
  for (int ti=0;ti<4;++ti) {
    int ig = i0 + ti*16 + l15;
    int t = tbase + ig;
    float sd = __expf(acs_i[ti]);
    #pragma unroll
    for (int tm=0;tm<4;++tm) {
      int ch0 = h*64 + tm*16 + l4*4;
      u16x4 gv = *(const u16x4*)&zx[(size_t)t*ZXW + ch0];
      u16x4 out;
      #pragma unroll
      for (int q=0;q<4;++q) {
        float yv = accY[tm][ti][q] + sd * oacc[tm][ti][q];
        yv *= siluf_(b2f(gv[q]));
        out[q] = f2b(yv);
      }
      *(u16x4*)&ybf[(size_t)t*DIN + ch0] = out;
    }
  }
}

// ---------------- RMS groupnorm, bf16 in-place ----------------
__global__ __launch_bounds__(256)
void groupnorm_bf16_kernel(unsigned short* __restrict__ y, const float* __restrict__ norm_w) {
  int bid = blockIdx.x;
  int g = bid % G;
  int t = bid / G;
  unsigned short* yp = y + (size_t)t*DIN + g*GROUP_SIZE;
  int tid = threadIdx.x;
  u16x4 v = *(const u16x4*)&yp[tid*4];
  float f[4]; float ss = 0.f;
  #pragma unroll
  for (int j=0;j<4;++j) { f[j] = b2f(v[j]); ss += f[j]*f[j]; }
  #pragma unroll
  for (int off = 32; off > 0; off >>= 1) ss += __shfl_xor(ss, off);
  __shared__ float wsum[4];
  int wave = tid >> 6;
  if ((tid & 63) == 0) wsum[wave] = ss;
  __syncthreads();
  float tot = wsum[0]+wsum[1]+wsum[2]+wsum[3];
  float rs = rsqrtf(tot/(float)GROUP_SIZE + 1e-5f);
  const float* nw = norm_w + g*GROUP_SIZE + tid*4;
  u16x4 o;
  #pragma unroll
  for (int j=0;j<4;++j) o[j] = f2b(f[j] * rs * nw[j]);
  *(u16x4*)&yp[tid*4] = o;
}

extern "C" void kernel_launch(void* const* d_in, const int* in_sizes, int n_in,
                              void* d_out, int out_size, void* d_ws, size_t ws_size,
                              hipStream_t stream) {
  const float* hs        = (const float*)d_in[0];
  const float* in_proj_w = (const float*)d_in[1];
  const float* conv_w    = (const float*)d_in[2];
  const float* conv_b    = (const float*)d_in[3];
  const float* dt_bias   = (const float*)d_in[4];
  const float* A_log     = (const float*)d_in[5];
  const float* Dp        = (const float*)d_in[6];
  const float* norm_w    = (const float*)d_in[7];
  const float* out_proj_w= (const float*)d_in[8];
  float* outp = (float*)d_out;

  char* ws = (char*)d_ws;
  __hip_bfloat16* zx_bf = (__hip_bfloat16*)ws;                      // NT*ZXW*2 = 150,994,944
  char* p = ws + (size_t)NT*ZXW*2;
  __hip_bfloat16* B_bf  = (__hip_bfloat16*)p; p += (size_t)NT*G*NSTATE*2;     // 8,388,608
  __hip_bfloat16* C_bf  = (__hip_bfloat16*)p; p += (size_t)NT*G*NSTATE*2;     // 8,388,608
  __hip_bfloat16* BT    = (__hip_bfloat16*)p; p += (size_t)NT*G*NSTATE*2;     // 8,388,608
  float* states = (float*)p;  p += (size_t)BATCH*NC*NH*HD*NSTATE*4;           // 67,108,864
  __hip_bfloat16* y_bf  = (__hip_bfloat16*)p; p += (size_t)NT*DIN*2;          // 67,108,864
  float* dtb    = (float*)p;  p += (size_t)NT*NH*4;                            // 2,097,152
  float* Acs    = (float*)p;  p += (size_t)BATCH*NH*NC*CS*4;                   // 2,097,152
  // dt split-K partials alias y_bf (dead until y_mfma): DTSK*NT*NH*4 = 33.5 MB
  float* dt_part = (float*)y_bf;
  // overlapped region F
  char* F = p;
  __hip_bfloat16* w_in_bf   = (__hip_bfloat16*)F;                   // ZXW x HID bf16 (150,994,944)
  __hip_bfloat16* xsT       = (__hip_bfloat16*)F;                   // after in_proj done
  __hip_bfloat16* xwT       = (__hip_bfloat16*)(F + 67108864);
  __hip_bfloat16* hs_bf     = (__hip_bfloat16*)(F + 150994944);     // until in_proj done
  __hip_bfloat16* states_bf = (__hip_bfloat16*)(F + 150994944);     // after recurrence (hs_bf dead)
  char* F2 = F + 150994944 + 33554432;
  __hip_bfloat16* w_out_bf  = (__hip_bfloat16*)F2;                  // 67,108,864

  // dt columns in fp32 (precision-critical), split-K for parallelism
  dt_gemm_splitk<<<dim3(DTSK, NT/128), 256, 0, stream>>>(hs, in_proj_w + (size_t)ZXW*HID, dt_part);
  dt_scan_kernel<<<BATCH*NH*NC, CS, 0, stream>>>(dt_part, dt_bias, A_log, dtb, Acs);

  // all casts in one launch
  cast3_kernel<<<4096, 256, 0, stream>>>(hs, hs_bf, in_proj_w, w_in_bf, out_proj_w, w_out_bf);

  // in_proj: M=4096, N=ZXW=18432 (72x256 exactly), K=4096 -> 1152 blocks
  gemm_bf16_256<true><<<dim3((NT/256)*(ZXW/256)), 512, 0, stream>>>(
      hs_bf, w_in_bf, zx_bf, NT, ZXW, HID);

  // fused conv+silu+transpose+scaling (replaces conv_silu + prep_xt + transpose)
  conv_fused_kernel<<<dim3(NT/64, CONV_DIM/64), 256, 0, stream>>>(
      zx_bf, conv_w, conv_b, dtb, Acs, xsT, xwT, B_bf, C_bf, BT);

  chunk_states_mfma<<<dim3(NH, BATCH*NC), 256, 0, stream>>>(xwT, BT, states);
  state_recurrence_kernel<<<(BATCH*NH*HD*NSTATE)/256, 256, 0, stream>>>(states, Acs, states_bf);
  y_mfma_kernel<<<dim3(NH, BATCH*NC), 256, 0, stream>>>(zx_bf, C_bf, B_bf, xsT, states_bf, dtb, Acs, Dp, y_bf);
  groupnorm_bf16_kernel<<<NT*G, 256, 0, stream>>>((unsigned short*)y_bf, norm_w);

  // out_proj: M=4096, N=4096, K=8192 -> 256 blocks
  gemm_bf16_256<false><<<dim3((NT/256)*(HID/256)), 512, 0, stream>>>(
      y_bf, w_out_bf, outp, NT, HID, DIN);
}

// Round 13
// 1798.457 us; speedup vs baseline: 1.0864x; 1.0095x over previous
//
#include <hip/hip_runtime.h>
#include <hip/hip_bf16.h>
#include <math.h>

#define HID 4096
#define NH 128
#define HD 64
#define DIN 8192      // NH*HD
#define G 8
#define NSTATE 128
#define CS 256
#define GROUP_SIZE 1024
#define CONV_DIM 10240  // DIN + 2*G*NSTATE
#define ZXW 18432       // DIN + CONV_DIM = 72*256 (dt columns handled by fp32 path)
#define BATCH 2
#define SEQ 2048
#define NT (BATCH*SEQ)  // 4096 tokens
#define NC 8            // SEQ/CS
#define DTSK 16         // split-K factor for the fp32 dt GEMM

typedef __attribute__((ext_vector_type(8))) short bf16x8;
typedef __attribute__((ext_vector_type(4))) float f32x4;
typedef __attribute__((ext_vector_type(8))) unsigned short u16x8;
typedef __attribute__((ext_vector_type(4))) unsigned short u16x4;

__device__ __forceinline__ float sigmoidf_(float x){ return 1.f/(1.f+expf(-x)); }
__device__ __forceinline__ float siluf_(float x){ return x*sigmoidf_(x); }
__device__ __forceinline__ float softplusf_(float x){ return (x>20.f)? x : log1pf(expf(x)); }
__device__ __forceinline__ float b2f(unsigned short u){ union{unsigned int i; float f;} x; x.i = ((unsigned int)u)<<16; return x.f; }
__device__ __forceinline__ unsigned short f2b(float f){ __hip_bfloat16 h = __float2bfloat16(f); return *(unsigned short*)&h; }

__device__ __forceinline__ void gload_lds16(const void* g, void* l) {
  __builtin_amdgcn_global_load_lds((const __attribute__((address_space(1))) unsigned int*)g,
                                   (__attribute__((address_space(3))) unsigned int*)l, 16, 0, 0);
}
__device__ __forceinline__ bf16x8 ld8bf(const __hip_bfloat16* p){ return *(const bf16x8*)p; }

__device__ __forceinline__ void cast8(const float* in, __hip_bfloat16* out) {
  const float4* p = (const float4*)in;
  float4 a = p[0], b = p[1];
  union { __hip_bfloat16 h[8]; int4 v; } o;
  o.h[0]=__float2bfloat16(a.x); o.h[1]=__float2bfloat16(a.y);
  o.h[2]=__float2bfloat16(a.z); o.h[3]=__float2bfloat16(a.w);
  o.h[4]=__float2bfloat16(b.x); o.h[5]=__float2bfloat16(b.y);
  o.h[6]=__float2bfloat16(b.z); o.h[7]=__float2bfloat16(b.w);
  *(int4*)out = o.v;
}

// ---------------- weight fp32->bf16 casts (hs handled by dt_gemm) ----------------
__global__ __launch_bounds__(256)
void cast2_kernel(const float* __restrict__ w_in, __hip_bfloat16* __restrict__ w_in_bf,
                  const float* __restrict__ w_out, __hip_bfloat16* __restrict__ w_out_bf) {
  const size_t n1 = (size_t)ZXW*HID/8;         // in_proj (first ZXW rows)
  const size_t n2 = (size_t)HID*DIN/8;         // out_proj
  const size_t ntot = n1 + n2;
  size_t i = (size_t)blockIdx.x * 256 + threadIdx.x;
  size_t stride = (size_t)gridDim.x * 256;
  for (; i < ntot; i += stride) {
    if (i < n1)  cast8(w_in + i*8,      w_in_bf + i*8);
    else         cast8(w_out+ (i-n1)*8, w_out_bf+ (i-n1)*8);
  }
}

// ---------------- 256x256 bf16 MFMA GEMM, 2-phase interleave, counted vmcnt ----------------
// (round-8 version: best measured, MfmaUtil 37%, bank conflicts 0)
template<bool OUT_BF16>
__global__ __launch_bounds__(512)
void gemm_bf16_256(const __hip_bfloat16* __restrict__ A, const __hip_bfloat16* __restrict__ B,
                   void* __restrict__ Cout, int M, int N, int K) {
  const int nMt = M >> 8, nNt = N >> 8;
  const int nwg = nMt * nNt;
  const int cpx = nwg >> 3;
  const int lin = blockIdx.x;
  const int swz = (lin & 7) * cpx + (lin >> 3);   // XCD-chunked (nwg%8==0)
  const int mt = swz % nMt, ntile = swz / nMt;    // M fastest -> B panel L2-hot
  const int rowBase = mt << 8;
  const int colBase = ntile << 8;

  __shared__ short As[4][8192];   // 4 x 16KB
  __shared__ short Bs[4][8192];

  const int tid = threadIdx.x;
  const int lane = tid & 63, wid = tid >> 6;
  const int wr = wid >> 2, wc = wid & 3;          // 2M x 4N wave grid
  const int l15 = lane & 15, l4 = lane >> 4;

  const int r0 = tid >> 2,        c0 = (tid & 3) ^ ((r0 >> 1) & 3);
  const int r1 = (512+tid) >> 2,  c1 = ((512+tid) & 3) ^ ((r1 >> 1) & 3);
  const __hip_bfloat16* gA0 = A + (size_t)(rowBase + r0)*K + c0*8;
  const __hip_bfloat16* gA1 = A + (size_t)(rowBase + r1)*K + c1*8;
  const __hip_bfloat16* gB0 = B + (size_t)(colBase + r0)*K + c0*8;
  const __hip_bfloat16* gB1 = B + (size_t)(colBase + r1)*K + c1*8;
  const int ld0 = wid*512, ld1 = 4096 + wid*512;

#define STAGE_A(q, kt) do { \
    gload_lds16(gA0 + (size_t)(kt)*32, (void*)&As[q][ld0]); \
    gload_lds16(gA1 + (size_t)(kt)*32, (void*)&As[q][ld1]); \
  } while(0)
#define STAGE_B(q, kt) do { \
    gload_lds16(gB0 + (size_t)(kt)*32, (void*)&Bs[q][ld0]); \
    gload_lds16(gB1 + (size_t)(kt)*32, (void*)&Bs[q][ld1]); \
  } while(0)

  int aoff[8], boff[4];
  #pragma unroll
  for (int m=0;m<8;++m){ int r = wr*128 + m*16 + l15; aoff[m] = r*32 + ((l4 ^ ((r>>1)&3))*8); }
  #pragma unroll
  for (int n=0;n<4;++n){ int r = wc*64  + n*16 + l15; boff[n] = r*32 + ((l4 ^ ((r>>1)&3))*8); }

  f32x4 acc[8][4] = {};
  const int NKT = K >> 5;

  STAGE_A(0,0); STAGE_B(0,0);
  STAGE_A(1,1); STAGE_B(1,1);
  STAGE_A(2,2); STAGE_B(2,2);
  asm volatile("s_waitcnt vmcnt(8)" ::: "memory");
  __builtin_amdgcn_s_barrier();

  for (int t = 0; t < NKT; ++t) {
    const short* ab = &As[t&3][0];
    const short* bb = &Bs[t&3][0];
    const int q3 = (t+3)&3;
    bf16x8 a[4], b[4], a2[4];
    // phase A
    #pragma unroll
    for (int m=0;m<4;++m) a[m] = *(const bf16x8*)&ab[aoff[m]];
    #pragma unroll
    for (int n=0;n<4;++n) b[n] = *(const bf16x8*)&bb[boff[n]];
    if (t + 3 < NKT) STAGE_A(q3, t+3);
    __builtin_amdgcn_s_barrier();
    asm volatile("s_waitcnt lgkmcnt(0)" ::: "memory");
    __builtin_amdgcn_sched_barrier(0);
    __builtin_amdgcn_s_setprio(1);
    #pragma unroll
    for (int m=0;m<4;++m)
      #pragma unroll
      for (int n=0;n<4;++n)
        acc[m][n] = __builtin_amdgcn_mfma_f32_16x16x32_bf16(a[m], b[n], acc[m][n], 0, 0, 0);
    __builtin_amdgcn_s_setprio(0);
    __builtin_amdgcn_s_barrier();
    // phase B
    #pragma unroll
    for (int m=0;m<4;++m) a2[m] = *(const bf16x8*)&ab[aoff[m+4]];
    if (t + 3 < NKT) STAGE_B(q3, t+3);
    const int rem = NKT - 1 - t;
    if (rem >= 3)      asm volatile("s_waitcnt vmcnt(8)" ::: "memory");
    else if (rem == 2) asm volatile("s_waitcnt vmcnt(4)" ::: "memory");
    else if (rem == 1) asm volatile("s_waitcnt vmcnt(0)" ::: "memory");
    __builtin_amdgcn_s_barrier();
    asm volatile("s_waitcnt lgkmcnt(0)" ::: "memory");
    __builtin_amdgcn_sched_barrier(0);
    __builtin_amdgcn_s_setprio(1);
    #pragma unroll
    for (int m=0;m<4;++m)
      #pragma unroll
      for (int n=0;n<4;++n)
        acc[m+4][n] = __builtin_amdgcn_mfma_f32_16x16x32_bf16(a2[m], b[n], acc[m+4][n], 0, 0, 0);
    __builtin_amdgcn_s_setprio(0);
    __builtin_amdgcn_s_barrier();
  }
#undef STAGE_A
#undef STAGE_B

  #pragma unroll
  for (int m=0;m<8;++m) {
    int row0 = rowBase + wr*128 + m*16 + l4*4;
    #pragma unroll
    for (int n=0;n<4;++n) {
      int col = colBase + wc*64 + n*16 + l15;
      #pragma unroll
      for (int j=0;j<4;++j) {
        if (OUT_BF16)
          ((__hip_bfloat16*)Cout)[(size_t)(row0+j)*N + col] = __float2bfloat16(acc[m][n][j]);
        else
          ((float*)Cout)[(size_t)(row0+j)*N + col] = acc[m][n][j];
      }
    }
  }
}

// ---------------- fp32 dt GEMM, split-K; also emits hs_bf (each element covered once) ----------------
__global__ __launch_bounds__(256)
void dt_gemm_splitk(const float* __restrict__ A, const float* __restrict__ B,
                    float* __restrict__ partial, __hip_bfloat16* __restrict__ hs_bf) {
  __shared__ float As[16][132];
  __shared__ float Bs[16][132];
  const int tid = threadIdx.x;
  const int tx = tid & 15, ty = tid >> 4;
  const int rowBase = blockIdx.y * 128;
  const int k0 = blockIdx.x * (HID/DTSK);
  float acc[8][8] = {};
  for (int kt = k0; kt < k0 + HID/DTSK; kt += 16) {
    for (int e = tid; e < 128*16; e += 256) {
      int r = e >> 4, c = e & 15;
      float av = A[(size_t)(rowBase + r) * HID + kt + c];
      As[c][r] = av;
      hs_bf[(size_t)(rowBase + r) * HID + kt + c] = __float2bfloat16(av);
      Bs[c][r] = B[(size_t)r * HID + kt + c];
    }
    __syncthreads();
    #pragma unroll
    for (int kk = 0; kk < 16; ++kk) {
      float a[8], bv[8];
      #pragma unroll
      for (int i = 0; i < 8; ++i) a[i] = As[kk][ty*8+i];
      #pragma unroll
      for (int j = 0; j < 8; ++j) bv[j] = Bs[kk][tx*8+j];
      #pragma unroll
      for (int i = 0; i < 8; ++i)
        #pragma unroll
        for (int j = 0; j < 8; ++j)
          acc[i][j] += a[i]*bv[j];
    }
    __syncthreads();
  }
  float* outp = partial + (size_t)blockIdx.x * NT * NH;
  for (int i = 0; i < 8; ++i) {
    size_t ro = (size_t)(rowBase + ty*8 + i) * NH + tx*8;
    #pragma unroll
    for (int j = 0; j < 8; ++j) outp[ro + j] = acc[i][j];
  }
}

// ---------------- dt: split-K reduce + softplus + per-chunk cumsum (merged) ----------------
__global__ __launch_bounds__(256)
void dt_scan_kernel(const float* __restrict__ partial, const float* __restrict__ dt_bias,
                    const float* __restrict__ A_log, float* __restrict__ dt_sp,
                    float* __restrict__ Acs) {
  int bid = blockIdx.x;       // (b*NH + h)*NC + c
  int c = bid % NC;
  int h = (bid / NC) % NH;
  int b = bid / (NC*NH);
  int k = threadIdx.x;
  int t = b*SEQ + c*CS + k;
  float raw = dt_bias[h];
  #pragma unroll
  for (int sk = 0; sk < DTSK; ++sk) raw += partial[(size_t)sk*NT*NH + (size_t)t*NH + h];
  float dtv = softplusf_(raw);
  dt_sp[(size_t)t*NH + h] = dtv;
  float adt = -expf(A_log[h]) * dtv;
  __shared__ float s[CS];
  s[k] = adt;
  __syncthreads();
  for (int off = 1; off < CS; off <<= 1) {
    float v = (k >= off) ? s[k-off] : 0.f;
    __syncthreads();
    s[k] += v;
    __syncthreads();
  }
  Acs[((size_t)(b*NH + h)*NC + c)*CS + k] = s[k];
}

// ---------------- fused conv+SiLU + transpose + dt scaling ----------------
__global__ __launch_bounds__(256)
void conv_fused_kernel(const __hip_bfloat16* __restrict__ zx, const float* __restrict__ w,
                       const float* __restrict__ bias,
                       const float* __restrict__ dt_sp, const float* __restrict__ Acs,
                       __hip_bfloat16* __restrict__ xsT, __hip_bfloat16* __restrict__ xwT,
                       __hip_bfloat16* __restrict__ Bbf, __hip_bfloat16* __restrict__ Cbf,
                       __hip_bfloat16* __restrict__ BT) {
  const int tt = blockIdx.x;
  const int ct = blockIdx.y;
  const int t0 = tt*64;
  const int ch0 = ct*64;               // conv-channel base
  const int tid = threadIdx.x;
  __shared__ unsigned short T[64][72];
  __shared__ float dts[64], ews[64];

  const bool isX = (ch0 < DIN);
  const bool isB = (ch0 >= DIN) && (ch0 < DIN + G*NSTATE);

  if (isX && tid < 64) {
    int h = ch0 >> 6;
    int t = t0 + tid;
    dts[tid] = dt_sp[(size_t)t*NH + h];
    int b = t0 >> 11, cc = (t0 >> 8) & 7, k0 = t0 & 255;
    const float* acs = Acs + ((size_t)(b*NH+h)*NC + cc)*CS;
    ews[tid] = __expf(acs[CS-1] - acs[k0 + tid]);
  }

  const int l0 = t0 & (SEQ-1);
  #pragma unroll
  for (int it = 0; it < 2; ++it) {
    int r = tid >> 2;
    int c8 = (tid & 3) + it*4;
    int cb = ch0 + c8*8;
    float acc[8];
    *(float4*)&acc[0] = *(const float4*)&bias[cb];
    *(float4*)&acc[4] = *(const float4*)&bias[cb+4];
    float4 wv[8];
    #pragma unroll
    for (int q=0;q<8;++q) wv[q] = *(const float4*)&w[(cb+q)*4];
    #pragma unroll
    for (int k=0;k<4;++k) {
      if (l0 + r - 3 + k >= 0) {
        u16x8 v = *(const u16x8*)&zx[(size_t)(t0+r-3+k)*ZXW + DIN + cb];
        #pragma unroll
        for (int q=0;q<8;++q) acc[q] += b2f(v[q]) * ((const float*)&wv[q])[k];
      }
    }
    u16x8 o;
    #pragma unroll
    for (int q=0;q<8;++q) o[q] = f2b(siluf_(acc[q]));
    if (isX || isB) {
      #pragma unroll
      for (int q=0;q<8;++q) T[c8*8+q][r] = o[q];
    }
    if (!isX) {
      if (isB) *(u16x8*)&Bbf[(size_t)(t0+r)*(G*NSTATE) + (cb - DIN)] = o;
      else     *(u16x8*)&Cbf[(size_t)(t0+r)*(G*NSTATE) + (cb - DIN - G*NSTATE)] = o;
    }
  }
  if (!isX && !isB) return;          // C-tile blocks exit uniformly (no barrier below)
  __syncthreads();
  #pragma unroll
  for (int it = 0; it < 2; ++it) {
    int ch = tid >> 2;
    int tc = (tid & 3) + it*4;
    u16x8 v = *(const u16x8*)&T[ch][tc*8];
    if (isX) {
      u16x8 a, wv2;
      #pragma unroll
      for (int q=0;q<8;++q) {
        float f = b2f(v[q]);
        float fs = f * dts[tc*8+q];
        a[q]   = f2b(fs);
        wv2[q] = f2b(fs * ews[tc*8+q]);
      }
      *(u16x8*)&xsT[(size_t)(ch0+ch)*NT + t0 + tc*8] = a;
      *(u16x8*)&xwT[(size_t)(ch0+ch)*NT + t0 + tc*8] = wv2;
    } else {
      *(u16x8*)&BT[(size_t)(ch0 - DIN + ch)*NT + t0 + tc*8] = v;
    }
  }
}

// ---------------- chunk states + inter-chunk recurrence, fused (prefix in registers) ----------------
// grid (NH, BATCH); per block: loop chunks c=0..7, compute chunk sum via MFMA, emit the
// PREFIX state (before this chunk) as bf16, then S = S*decay(c) + sum. Bit-identical to the
// previous two-kernel version; removes the fp32 states round-trip entirely.
__global__ __launch_bounds__(256)
void chunk_states_fused(const __hip_bfloat16* __restrict__ xwT, const __hip_bfloat16* __restrict__ BT,
                        const float* __restrict__ Acs, __hip_bfloat16* __restrict__ states_bf) {
  int h = blockIdx.x, b = blockIdx.y;
  int g = h >> 4;
  int tid = threadIdx.x, lane = tid & 63, w = tid >> 6;
  int l15 = lane & 15, l4 = lane >> 4;
  int n0 = w*32;
  f32x4 S[4][2] = {};
  for (int c = 0; c < NC; ++c) {
    int tbase = b*SEQ + c*CS;
    const __hip_bfloat16* xp = xwT + (size_t)(h*64 + l15)*NT + tbase + l4*8;
    const __hip_bfloat16* bp = BT + (size_t)(g*128 + n0 + l15)*NT + tbase + l4*8;
    f32x4 acc[4][2] = {};
    for (int kc = 0; kc < 8; ++kc) {
      bf16x8 xf[4], bf2[2];
      #pragma unroll
      for (int tm=0;tm<4;++tm) xf[tm] = ld8bf(xp + (size_t)(tm*16)*NT + kc*32);
      #pragma unroll
      for (int tn=0;tn<2;++tn) bf2[tn] = ld8bf(bp + (size_t)(tn*16)*NT + kc*32);
      #pragma unroll
      for (int tm=0;tm<4;++tm)
        #pragma unroll
        for (int tn=0;tn<2;++tn)
          acc[tm][tn] = __builtin_amdgcn_mfma_f32_16x16x32_bf16(xf[tm], bf2[tn], acc[tm][tn], 0, 0, 0);
    }
    __hip_bfloat16* out = states_bf + ((size_t)(b*NC + c)*NH + h)*(HD*NSTATE);
    float decay = expf(Acs[((size_t)(b*NH+h)*NC + c)*CS + CS-1]);
    #pragma unroll
    for (int tm=0;tm<4;++tm)
      #pragma unroll
      for (int tn=0;tn<2;++tn)
        #pragma unroll
        for (int q=0;q<4;++q) {
          out[(size_t)(tm*16 + l4*4 + q)*NSTATE + n0 + tn*16 + l15] = __float2bfloat16(S[tm][tn][q]);
          S[tm][tn][q] = S[tm][tn][q]*decay + acc[tm][tn][q];
        }
  }
}

// ---------------- Y via MFMA (wave-causal) ----------------
__global__ __launch_bounds__(256)
void y_mfma_kernel(const __hip_bfloat16* __restrict__ zx,
                   const __hip_bfloat16* __restrict__ Cn,
                   const __hip_bfloat16* __restrict__ Bn,
                   const __hip_bfloat16* __restrict__ xsT,
                   const __hip_bfloat16* __restrict__ Sbf,
                   const float* __restrict__ dt_sp,
                   const float* __restrict__ Acs,
                   const float* __restrict__ Dp,
                   __hip_bfloat16* __restrict__ ybf) {
  int h = blockIdx.x;
  int bc = blockIdx.y;
  int c = bc & 7, b = bc >> 3;
  int g = h >> 4;
  int tbase = b*SEQ + c*CS;
  int tid = threadIdx.x, lane = tid & 63, w = tid >> 6;
  int l15 = lane & 15, l4 = lane >> 4;
  int i0 = w*64;
  __shared__ float acs_s[CS];
  __shared__ unsigned short P[4][64][72];
  acs_s[tid] = Acs[((size_t)(b*NH+h)*NC + c)*CS + tid];
  __syncthreads();

  float acs_i[4], rd[4];
  float Dh = Dp[h];
  #pragma unroll
  for (int ti=0;ti<4;++ti) {
    int ig = i0 + ti*16 + l15;
    acs_i[ti] = acs_s[ig];
    rd[ti] = Dh / dt_sp[(size_t)(tbase+ig)*NH + h];
  }
  const __hip_bfloat16* Cbase = Cn + (size_t)tbase*1024 + g*128;
  const __hip_bfloat16* Bbase = Bn + (size_t)tbase*1024 + g*128;
  const __hip_bfloat16* xbase = xsT + (size_t)(h*64 + l15)*NT + tbase;

  f32x4 accY[4][4] = {};
  for (int jb = 0; jb <= w; ++jb) {
    int j0 = jb*64;
    f32x4 sacc[4][4] = {};
    for (int kc = 0; kc < 4; ++kc) {
      bf16x8 bfr[4], cfr[4];
      #pragma unroll
      for (int tj=0;tj<4;++tj) bfr[tj] = ld8bf(Bbase + (size_t)(j0 + tj*16 + l15)*1024 + kc*32 + l4*8);
      #pragma unroll
      for (int ti=0;ti<4;++ti) cfr[ti] = ld8bf(Cbase + (size_t)(i0 + ti*16 + l15)*1024 + kc*32 + l4*8);
      #pragma unroll
      for (int tj=0;tj<4;++tj)
        #pragma unroll
        for (int ti=0;ti<4;++ti)
          sacc[tj][ti] = __builtin_amdgcn_mfma_f32_16x16x32_bf16(bfr[tj], cfr[ti], sacc[tj][ti], 0, 0, 0);
    }
    #pragma unroll
    for (int tj=0;tj<4;++tj)
      #pragma unroll
      for (int ti=0;ti<4;++ti) {
        int ig = i0 + ti*16 + l15;
        float ai = acs_i[ti];
        u16x4 pk;
        #pragma unroll
        for (int q=0;q<4;++q) {
          int jg = j0 + tj*16 + l4*4 + q;
          float v = (jg <= ig) ? sacc[tj][ti][q] * __expf(ai - acs_s[jg]) : 0.f;
          if (jg == ig) v += rd[ti];
          pk[q] = f2b(v);
        }
        *(u16x4*)&P[w][ti*16 + l15][tj*16 + l4*4] = pk;
      }
    #pragma unroll
    for (int kc2 = 0; kc2 < 2; ++kc2) {
      bf16x8 xf[4], pf[4];
      #pragma unroll
      for (int tm=0;tm<4;++tm) xf[tm] = ld8bf(xbase + (size_t)(tm*16)*NT + j0 + kc2*32 + l4*8);
      #pragma unroll
      for (int ti=0;ti<4;++ti) pf[ti] = *(const bf16x8*)&P[w][ti*16 + l15][kc2*32 + l4*8];
      #pragma unroll
      for (int tm=0;tm<4;++tm)
        #pragma unroll
        for (int ti=0;ti<4;++ti)
          accY[tm][ti] = __builtin_amdgcn_mfma_f32_16x16x32_bf16(xf[tm], pf[ti], accY[tm][ti], 0, 0, 0);
    }
  }
  const __hip_bfloat16* Sb = Sbf + ((size_t)bc*NH + h)*(HD*NSTATE);
  f32x4 oacc[4][4] = {};
  for (int kc = 0; kc < 4; ++kc) {
    bf16x8 sf[4], cfr[4];
    #pragma unroll
    for (int tm=0;tm<4;++tm) sf[tm] = ld8bf(Sb + (size_t)(tm*16 + l15)*NSTATE + kc*32 + l4*8);
    #pragma unroll
    for (int ti=0;ti<4;++ti) cfr[ti] = ld8bf(Cbase + (size_t)(i0 + ti*16 + l15)*1024 + kc*32 + l4*8);
    #pragma unroll
    for (int tm=0;tm<4;++tm)
      #pragma unroll
      for (int ti=0;ti<4;++ti)
        oacc[tm][ti] = __builtin_amdgcn_mfma_f32_16x16x32_bf16(sf[tm], cfr[ti], oacc[tm][ti], 0, 0, 0);
  }
  #pragma unroll
  for (int ti=0;ti<4;++ti) {
    int ig = i0 + ti*16 + l15;
    int t = tbase + ig;
    float sd = __expf(acs_i[ti]);
    #pragma unroll
    for (int tm=0;tm<4;++tm) {
      int ch0 = h*64 + tm*16 + l4*4;
      u16x4 gv = *(const u16x4*)&zx[(size_t)t*ZXW + ch0];
      u16x4 out;
      #pragma unroll
      for (int q=0;q<4;++q) {
        float yv = accY[tm][ti][q] + sd * oacc[tm][ti][q];
        yv *= siluf_(b2f(gv[q]));
        out[q] = f2b(yv);
      }
      *(u16x4*)&ybf[(size_t)t*DIN + ch0] = out;
    }
  }
}

// ---------------- RMS groupnorm, bf16 in-place ----------------
__global__ __launch_bounds__(256)
void groupnorm_bf16_kernel(unsigned short* __restrict__ y, const float* __restrict__ norm_w) {
  int bid = blockIdx.x;
  int g = bid % G;
  int t = bid / G;
  unsigned short* yp = y + (size_t)t*DIN + g*GROUP_SIZE;
  int tid = threadIdx.x;
  u16x4 v = *(const u16x4*)&yp[tid*4];
  float f[4]; float ss = 0.f;
  #pragma unroll
  for (int j=0;j<4;++j) { f[j] = b2f(v[j]); ss += f[j]*f[j]; }
  #pragma unroll
  for (int off = 32; off > 0; off >>= 1) ss += __shfl_xor(ss, off);
  __shared__ float wsum[4];
  int wave = tid >> 6;
  if ((tid & 63) == 0) wsum[wave] = ss;
  __syncthreads();
  float tot = wsum[0]+wsum[1]+wsum[2]+wsum[3];
  float rs = rsqrtf(tot/(float)GROUP_SIZE + 1e-5f);
  const float* nw = norm_w + g*GROUP_SIZE + tid*4;
  u16x4 o;
  #pragma unroll
  for (int j=0;j<4;++j) o[j] = f2b(f[j] * rs * nw[j]);
  *(u16x4*)&yp[tid*4] = o;
}

extern "C" void kernel_launch(void* const* d_in, const int* in_sizes, int n_in,
                              void* d_out, int out_size, void* d_ws, size_t ws_size,
                              hipStream_t stream) {
  const float* hs        = (const float*)d_in[0];
  const float* in_proj_w = (const float*)d_in[1];
  const float* conv_w    = (const float*)d_in[2];
  const float* conv_b    = (const float*)d_in[3];
  const float* dt_bias   = (const float*)d_in[4];
  const float* A_log     = (const float*)d_in[5];
  const float* Dp        = (const float*)d_in[6];
  const float* norm_w    = (const float*)d_in[7];
  const float* out_proj_w= (const float*)d_in[8];
  float* outp = (float*)d_out;

  char* ws = (char*)d_ws;
  __hip_bfloat16* zx_bf = (__hip_bfloat16*)ws;                      // NT*ZXW*2 = 150,994,944
  char* p = ws + (size_t)NT*ZXW*2;
  __hip_bfloat16* B_bf  = (__hip_bfloat16*)p; p += (size_t)NT*G*NSTATE*2;     // 8,388,608
  __hip_bfloat16* C_bf  = (__hip_bfloat16*)p; p += (size_t)NT*G*NSTATE*2;     // 8,388,608
  __hip_bfloat16* BT    = (__hip_bfloat16*)p; p += (size_t)NT*G*NSTATE*2;     // 8,388,608
  __hip_bfloat16* y_bf  = (__hip_bfloat16*)p; p += (size_t)NT*DIN*2;          // 67,108,864
  float* dtb    = (float*)p;  p += (size_t)NT*NH*4;                            // 2,097,152
  float* Acs    = (float*)p;  p += (size_t)BATCH*NH*NC*CS*4;                   // 2,097,152
  // dt split-K partials alias y_bf (dead until y_mfma): DTSK*NT*NH*4 = 33.5 MB
  float* dt_part = (float*)y_bf;
  // overlapped region F
  char* F = p;
  __hip_bfloat16* w_in_bf   = (__hip_bfloat16*)F;                   // ZXW x HID bf16 (150,994,944)
  __hip_bfloat16* xsT       = (__hip_bfloat16*)F;                   // after in_proj done
  __hip_bfloat16* xwT       = (__hip_bfloat16*)(F + 67108864);
  __hip_bfloat16* hs_bf     = (__hip_bfloat16*)(F + 150994944);     // until in_proj done
  __hip_bfloat16* states_bf = (__hip_bfloat16*)(F + 150994944);     // after in_proj (hs_bf dead)
  char* F2 = F + 150994944 + 33554432;
  __hip_bfloat16* w_out_bf  = (__hip_bfloat16*)F2;                  // 67,108,864

  // dt columns in fp32 (precision-critical), split-K; also emits hs_bf
  dt_gemm_splitk<<<dim3(DTSK, NT/128), 256, 0, stream>>>(hs, in_proj_w + (size_t)ZXW*HID, dt_part, hs_bf);
  dt_scan_kernel<<<BATCH*NH*NC, CS, 0, stream>>>(dt_part, dt_bias, A_log, dtb, Acs);

  // weight casts
  cast2_kernel<<<4096, 256, 0, stream>>>(in_proj_w, w_in_bf, out_proj_w, w_out_bf);

  // in_proj: M=4096, N=ZXW=18432 (72x256 exactly), K=4096 -> 1152 blocks
  gemm_bf16_256<true><<<dim3((NT/256)*(ZXW/256)), 512, 0, stream>>>(
      hs_bf, w_in_bf, zx_bf, NT, ZXW, HID);

  // fused conv+silu+transpose+scaling
  conv_fused_kernel<<<dim3(NT/64, CONV_DIM/64), 256, 0, stream>>>(
      zx_bf, conv_w, conv_b, dtb, Acs, xsT, xwT, B_bf, C_bf, BT);

  // fused chunk-state sums + inter-chunk recurrence (register prefix)
  chunk_states_fused<<<dim3(NH, BATCH), 256, 0, stream>>>(xwT, BT, Acs, states_bf);

  y_mfma_kernel<<<dim3(NH, BATCH*NC), 256, 0, stream>>>(zx_bf, C_bf, B_bf, xsT, states_bf, dtb, Acs, Dp, y_bf);
  groupnorm_bf16_kernel<<<NT*G, 256, 0, stream>>>((unsigned short*)y_bf, norm_w);

  // out_proj: M=4096, N=4096, K=8192 -> 256 blocks
  gemm_bf16_256<false><<<dim3((NT/256)*(HID/256)), 512, 0, stream>>>(
      y_bf, w_out_bf, outp, NT, HID, DIN);
}

// Round 14
// 1782.868 us; speedup vs baseline: 1.0958x; 1.0087x over previous
//
#include <hip/hip_runtime.h>
#include <hip/hip_bf16.h>
#include <math.h>

#define HID 4096
#define NH 128
#define HD 64
#define DIN 8192      // NH*HD
#define G 8
#define NSTATE 128
#define CS 256
#define GROUP_SIZE 1024
#define CONV_DIM 10240  // DIN + 2*G*NSTATE
#define ZXW 18432       // DIN + CONV_DIM = 72*256 (dt columns handled by fp32 path)
#define BATCH 2
#define SEQ 2048
#define NT (BATCH*SEQ)  // 4096 tokens
#define NC 8            // SEQ/CS
#define DTSK 16         // split-K factor for the fp32 dt GEMM

typedef __attribute__((ext_vector_type(8))) short bf16x8;
typedef __attribute__((ext_vector_type(4))) float f32x4;
typedef __attribute__((ext_vector_type(8))) unsigned short u16x8;
typedef __attribute__((ext_vector_type(4))) unsigned short u16x4;

__device__ __forceinline__ float sigmoidf_(float x){ return 1.f/(1.f+expf(-x)); }
__device__ __forceinline__ float siluf_(float x){ return x*sigmoidf_(x); }
__device__ __forceinline__ float softplusf_(float x){ return (x>20.f)? x : log1pf(expf(x)); }
__device__ __forceinline__ float b2f(unsigned short u){ union{unsigned int i; float f;} x; x.i = ((unsigned int)u)<<16; return x.f; }
__device__ __forceinline__ unsigned short f2b(float f){ __hip_bfloat16 h = __float2bfloat16(f); return *(unsigned short*)&h; }

__device__ __forceinline__ void gload_lds16(const void* g, void* l) {
  __builtin_amdgcn_global_load_lds((const __attribute__((address_space(1))) unsigned int*)g,
                                   (__attribute__((address_space(3))) unsigned int*)l, 16, 0, 0);
}
__device__ __forceinline__ bf16x8 ld8bf(const __hip_bfloat16* p){ return *(const bf16x8*)p; }

__device__ __forceinline__ void cast8(const float* in, __hip_bfloat16* out) {
  const float4* p = (const float4*)in;
  float4 a = p[0], b = p[1];
  union { __hip_bfloat16 h[8]; int4 v; } o;
  o.h[0]=__float2bfloat16(a.x); o.h[1]=__float2bfloat16(a.y);
  o.h[2]=__float2bfloat16(a.z); o.h[3]=__float2bfloat16(a.w);
  o.h[4]=__float2bfloat16(b.x); o.h[5]=__float2bfloat16(b.y);
  o.h[6]=__float2bfloat16(b.z); o.h[7]=__float2bfloat16(b.w);
  *(int4*)out = o.v;
}

// ---------------- weight fp32->bf16 casts (hs handled by dt_gemm) ----------------
__global__ __launch_bounds__(256)
void cast2_kernel(const float* __restrict__ w_in, __hip_bfloat16* __restrict__ w_in_bf,
                  const float* __restrict__ w_out, __hip_bfloat16* __restrict__ w_out_bf) {
  const size_t n1 = (size_t)ZXW*HID/8;
  const size_t n2 = (size_t)HID*DIN/8;
  const size_t ntot = n1 + n2;
  size_t i = (size_t)blockIdx.x * 256 + threadIdx.x;
  size_t stride = (size_t)gridDim.x * 256;
  for (; i < ntot; i += stride) {
    if (i < n1)  cast8(w_in + i*8,      w_in_bf + i*8);
    else         cast8(w_out+ (i-n1)*8, w_out_bf+ (i-n1)*8);
  }
}

// ---------------- 256x256 bf16 MFMA GEMM — m201-style 8-phase schedule ----------------
// BK=64, 2 K-tiles/iter (buf0=even, buf1=odd tile), per phase: {quadrant ds_reads ||
// stage ONE half-tile (2 gload_lds)} -> barrier -> lgkm(0) -> 16 MFMA -> barrier.
// vmcnt(6) at ph4, vmcnt(4) at ph7 (never 0 mid-loop). LDS half-tile layout [ks][128][32]
// with round-8's measured-zero-conflict XOR swizzle (granule ^= (row>>1)&3, both sides).
// Staging safety (slot overwritten >=1 barrier after its last read):
//   B-half of tile T last read ph1/ph5 -> staged ph2/ph6+ ; A-half last read ph2/ph6 -> ph3/ph7+.
// vmcnt accounting (2 loads/phase/wave): ph4's vmcnt(6) ensures odd tile's 4 half-tiles
// (prev ph6,ph7 + this ph0,ph1); ph7's vmcnt(4) ensures even tile T+2 (ph2..ph5).
template<bool OUT_BF16>
__global__ __launch_bounds__(512, 2)
void gemm_bf16_256(const __hip_bfloat16* __restrict__ A, const __hip_bfloat16* __restrict__ B,
                   void* __restrict__ Cout, int M, int N, int K) {
  const int nMt = M >> 8, nNt = N >> 8;
  const int nwg = nMt * nNt;
  const int cpx = nwg >> 3;
  const int lin = blockIdx.x;
  const int swz = (lin & 7) * cpx + (lin >> 3);   // XCD-chunked (nwg%8==0)
  const int mt = swz % nMt, ntile = swz / nMt;    // M fastest -> B panel L2-hot
  const int rowBase = mt << 8;
  const int colBase = ntile << 8;

  // [buf][half] -> 8192 shorts each: [ks(2)][row(128)][32]
  __shared__ short As[2][2][8192];
  __shared__ short Bs[2][2][8192];

  const int tid = threadIdx.x;
  const int lane = tid & 63, wid = tid >> 6;
  const int wr = wid >> 2, wc = wid & 3;          // 2M x 4N wave grid
  const int l15 = lane & 15, l4 = lane >> 4;

  // staging thread map: row = tid>>2 (0..127), source granule = (tid&3)^((row>>1)&3)
  const int r0 = tid >> 2;
  const int c0 = (tid & 3) ^ ((r0 >> 1) & 3);
  const __hip_bfloat16* gA = A + (size_t)(rowBase + r0)*K + c0*8;
  const __hip_bfloat16* gB = B + (size_t)(colBase + r0)*K + c0*8;
  const int wdst = wid * 512;                     // wave-uniform LDS dest (shorts)

  // stage half-tile `h` of K-tile `kt` of operand into buffer slot Ld[8192]
#define STG(Ld, gp, h, kt) do { \
    gload_lds16(gp + (size_t)((h)*128)*K + (size_t)(kt)*64,      (void*)&(Ld)[wdst]); \
    gload_lds16(gp + (size_t)((h)*128)*K + (size_t)(kt)*64 + 32, (void*)&(Ld)[4096 + wdst]); \
  } while(0)

  // frag read offsets (shorts) within a half-tile slot; +ks*4096 for k-half
  const int xg = (l4 ^ ((l15 >> 1) & 3)) * 8;
  int aofs[8], bofs[4];
  #pragma unroll
  for (int m=0;m<8;++m) aofs[m] = (m*16 + l15)*32 + xg;
  #pragma unroll
  for (int n=0;n<4;++n) bofs[n] = ((wc&1)*64 + n*16 + l15)*32 + xg;

  bf16x8 Af[4][2], Bf[4][2];
  f32x4 acc[8][4] = {};

#define RDA(bb, mh) do { \
    const short* s_ = &As[bb][wr][0]; \
    _Pragma("unroll") for (int m=0;m<4;++m) { \
      Af[m][0] = *(const bf16x8*)&s_[aofs[(mh)*4+m]]; \
      Af[m][1] = *(const bf16x8*)&s_[4096 + aofs[(mh)*4+m]]; } \
  } while(0)
#define RDB(bb, nh) do { \
    const short* s_ = &Bs[bb][wc>>1][0]; \
    _Pragma("unroll") for (int n=0;n<2;++n) { \
      Bf[(nh)*2+n][0] = *(const bf16x8*)&s_[bofs[(nh)*2+n]]; \
      Bf[(nh)*2+n][1] = *(const bf16x8*)&s_[4096 + bofs[(nh)*2+n]]; } \
  } while(0)
#define MFQ(mh, nh) do { \
    __builtin_amdgcn_s_setprio(1); \
    _Pragma("unroll") for (int m=0;m<4;++m) \
      _Pragma("unroll") for (int n=0;n<2;++n) \
        _Pragma("unroll") for (int ks=0;ks<2;++ks) \
          acc[(mh)*4+m][(nh)*2+n] = __builtin_amdgcn_mfma_f32_16x16x32_bf16( \
              Af[m][ks], Bf[(nh)*2+n][ks], acc[(mh)*4+m][(nh)*2+n], 0, 0, 0); \
    __builtin_amdgcn_s_setprio(0); \
  } while(0)
#define FENCE() do { \
    __builtin_amdgcn_s_barrier(); \
    asm volatile("s_waitcnt lgkmcnt(0)" ::: "memory"); \
    __builtin_amdgcn_sched_barrier(0); \
  } while(0)
#define ENDP() __builtin_amdgcn_s_barrier()

  const int NKT = K >> 6;       // K-tiles of 64 (even: 64 or 128)
  const int NU = NKT >> 1;

  // prologue: tile0 (all 4 halves) + tile1 (lo halves); vmcnt(4) -> tile0 complete
  STG(Bs[0][0], gB, 0, 0); STG(As[0][0], gA, 0, 0);
  STG(Bs[0][1], gB, 1, 0); STG(As[0][1], gA, 1, 0);
  STG(Bs[1][0], gB, 0, 1); STG(As[1][0], gA, 0, 1);
  asm volatile("s_waitcnt vmcnt(4)" ::: "memory");
  __builtin_amdgcn_s_barrier();

  for (int u = 0; u < NU; ++u) {
    const int T = 2*u;
    const bool last = (u == NU-1);
    // ph0: quadrant (m0-3, n0-1) of tile T (buf0); stage B_hi(T+1)
    RDA(0, 0); RDB(0, 0);
    STG(Bs[1][1], gB, 1, T+1);
    FENCE(); MFQ(0, 0); ENDP();
    // ph1: (m0-3, n2-3); stage A_hi(T+1)
    RDB(0, 1);
    STG(As[1][1], gA, 1, T+1);
    FENCE(); MFQ(0, 1); ENDP();
    // ph2: (m4-7, n2-3); stage B_lo(T+2)
    RDA(0, 1);
    if (!last) STG(Bs[0][0], gB, 0, T+2);
    FENCE(); MFQ(1, 1); ENDP();
    // ph3: (m4-7, n0-1); stage A_lo(T+2)
    if (!last) STG(As[0][0], gA, 0, T+2);
    FENCE(); MFQ(1, 0); ENDP();
    // ph4: tile T+1 (buf1) quadrant (m0-3, n0-1); stage B_hi(T+2); vmcnt gate for T+1
    RDA(1, 0); RDB(1, 0);
    if (!last) { STG(Bs[0][1], gB, 1, T+2); asm volatile("s_waitcnt vmcnt(6)" ::: "memory"); }
    else       { asm volatile("s_waitcnt vmcnt(0)" ::: "memory"); }
    FENCE(); MFQ(0, 0); ENDP();
    // ph5: (m0-3, n2-3); stage A_hi(T+2)
    RDB(1, 1);
    if (!last) STG(As[0][1], gA, 1, T+2);
    FENCE(); MFQ(0, 1); ENDP();
    // ph6: (m4-7, n2-3); stage B_lo(T+3)
    RDA(1, 1);
    if (!last) STG(Bs[1][0], gB, 0, T+3);
    FENCE(); MFQ(1, 1); ENDP();
    // ph7: (m4-7, n0-1); stage A_lo(T+3); vmcnt gate for T+2
    if (!last) { STG(As[1][0], gA, 0, T+3); asm volatile("s_waitcnt vmcnt(4)" ::: "memory"); }
    FENCE(); MFQ(1, 0); ENDP();
  }
#undef STG
#undef RDA
#undef RDB
#undef MFQ
#undef FENCE
#undef ENDP

  #pragma unroll
  for (int m=0;m<8;++m) {
    int row0 = rowBase + wr*128 + m*16 + l4*4;
    #pragma unroll
    for (int n=0;n<4;++n) {
      int col = colBase + wc*64 + n*16 + l15;
      #pragma unroll
      for (int j=0;j<4;++j) {
        if (OUT_BF16)
          ((__hip_bfloat16*)Cout)[(size_t)(row0+j)*N + col] = __float2bfloat16(acc[m][n][j]);
        else
          ((float*)Cout)[(size_t)(row0+j)*N + col] = acc[m][n][j];
      }
    }
  }
}

// ---------------- fp32 dt GEMM, split-K; also emits hs_bf ----------------
__global__ __launch_bounds__(256)
void dt_gemm_splitk(const float* __restrict__ A, const float* __restrict__ B,
                    float* __restrict__ partial, __hip_bfloat16* __restrict__ hs_bf) {
  __shared__ float As[16][132];
  __shared__ float Bs[16][132];
  const int tid = threadIdx.x;
  const int tx = tid & 15, ty = tid >> 4;
  const int rowBase = blockIdx.y * 128;
  const int k0 = blockIdx.x * (HID/DTSK);
  float acc[8][8] = {};
  for (int kt = k0; kt < k0 + HID/DTSK; kt += 16) {
    for (int e = tid; e < 128*16; e += 256) {
      int r = e >> 4, c = e & 15;
      float av = A[(size_t)(rowBase + r) * HID + kt + c];
      As[c][r] = av;
      hs_bf[(size_t)(rowBase + r) * HID + kt + c] = __float2bfloat16(av);
      Bs[c][r] = B[(size_t)r * HID + kt + c];
    }
    __syncthreads();
    #pragma unroll
    for (int kk = 0; kk < 16; ++kk) {
      float a[8], bv[8];
      #pragma unroll
      for (int i = 0; i < 8; ++i) a[i] = As[kk][ty*8+i];
      #pragma unroll
      for (int j = 0; j < 8; ++j) bv[j] = Bs[kk][tx*8+j];
      #pragma unroll
      for (int i = 0; i < 8; ++i)
        #pragma unroll
        for (int j = 0; j < 8; ++j)
          acc[i][j] += a[i]*bv[j];
    }
    __syncthreads();
  }
  float* outp = partial + (size_t)blockIdx.x * NT * NH;
  for (int i = 0; i < 8; ++i) {
    size_t ro = (size_t)(rowBase + ty*8 + i) * NH + tx*8;
    #pragma unroll
    for (int j = 0; j < 8; ++j) outp[ro + j] = acc[i][j];
  }
}

// ---------------- dt: split-K reduce + softplus + per-chunk cumsum ----------------
__global__ __launch_bounds__(256)
void dt_scan_kernel(const float* __restrict__ partial, const float* __restrict__ dt_bias,
                    const float* __restrict__ A_log, float* __restrict__ dt_sp,
                    float* __restrict__ Acs) {
  int bid = blockIdx.x;       // (b*NH + h)*NC + c
  int c = bid % NC;
  int h = (bid / NC) % NH;
  int b = bid / (NC*NH);
  int k = threadIdx.x;
  int t = b*SEQ + c*CS + k;
  float raw = dt_bias[h];
  #pragma unroll
  for (int sk = 0; sk < DTSK; ++sk) raw += partial[(size_t)sk*NT*NH + (size_t)t*NH + h];
  float dtv = softplusf_(raw);
  dt_sp[(size_t)t*NH + h] = dtv;
  float adt = -expf(A_log[h]) * dtv;
  __shared__ float s[CS];
  s[k] = adt;
  __syncthreads();
  for (int off = 1; off < CS; off <<= 1) {
    float v = (k >= off) ? s[k-off] : 0.f;
    __syncthreads();
    s[k] += v;
    __syncthreads();
  }
  Acs[((size_t)(b*NH + h)*NC + c)*CS + k] = s[k];
}

// ---------------- fused conv+SiLU + transpose + dt scaling ----------------
__global__ __launch_bounds__(256)
void conv_fused_kernel(const __hip_bfloat16* __restrict__ zx, const float* __restrict__ w,
                       const float* __restrict__ bias,
                       const float* __restrict__ dt_sp, const float* __restrict__ Acs,
                       __hip_bfloat16* __restrict__ xsT, __hip_bfloat16* __restrict__ xwT,
                       __hip_bfloat16* __restrict__ Bbf, __hip_bfloat16* __restrict__ Cbf,
                       __hip_bfloat16* __restrict__ BT) {
  const int tt = blockIdx.x;
  const int ct = blockIdx.y;
  const int t0 = tt*64;
  const int ch0 = ct*64;
  const int tid = threadIdx.x;
  __shared__ unsigned short T[64][72];
  __shared__ float dts[64], ews[64];

  const bool isX = (ch0 < DIN);
  const bool isB = (ch0 >= DIN) && (ch0 < DIN + G*NSTATE);

  if (isX && tid < 64) {
    int h = ch0 >> 6;
    int t = t0 + tid;
    dts[tid] = dt_sp[(size_t)t*NH + h];
    int b = t0 >> 11, cc = (t0 >> 8) & 7, k0 = t0 & 255;
    const float* acs = Acs + ((size_t)(b*NH+h)*NC + cc)*CS;
    ews[tid] = __expf(acs[CS-1] - acs[k0 + tid]);
  }

  const int l0 = t0 & (SEQ-1);
  #pragma unroll
  for (int it = 0; it < 2; ++it) {
    int r = tid >> 2;
    int c8 = (tid & 3) + it*4;
    int cb = ch0 + c8*8;
    float acc[8];
    *(float4*)&acc[0] = *(const float4*)&bias[cb];
    *(float4*)&acc[4] = *(const float4*)&bias[cb+4];
    float4 wv[8];
    #pragma unroll
    for (int q=0;q<8;++q) wv[q] = *(const float4*)&w[(cb+q)*4];
    #pragma unroll
    for (int k=0;k<4;++k) {
      if (l0 + r - 3 + k >= 0) {
        u16x8 v = *(const u16x8*)&zx[(size_t)(t0+r-3+k)*ZXW + DIN + cb];
        #pragma unroll
        for (int q=0;q<8;++q) acc[q] += b2f(v[q]) * ((const float*)&wv[q])[k];
      }
    }
    u16x8 o;
    #pragma unroll
    for (int q=0;q<8;++q) o[q] = f2b(siluf_(acc[q]));
    if (isX || isB) {
      #pragma unroll
      for (int q=0;q<8;++q) T[c8*8+q][r] = o[q];
    }
    if (!isX) {
      if (isB) *(u16x8*)&Bbf[(size_t)(t0+r)*(G*NSTATE) + (cb - DIN)] = o;
      else     *(u16x8*)&Cbf[(size_t)(t0+r)*(G*NSTATE) + (cb - DIN - G*NSTATE)] = o;
    }
  }
  if (!isX && !isB) return;
  __syncthreads();
  #pragma unroll
  for (int it = 0; it < 2; ++it) {
    int ch = tid >> 2;
    int tc = (tid & 3) + it*4;
    u16x8 v = *(const u16x8*)&T[ch][tc*8];
    if (isX) {
      u16x8 a, wv2;
      #pragma unroll
      for (int q=0;q<8;++q) {
        float f = b2f(v[q]);
        float fs = f * dts[tc*8+q];
        a[q]   = f2b(fs);
        wv2[q] = f2b(fs * ews[tc*8+q]);
      }
      *(u16x8*)&xsT[(size_t)(ch0+ch)*NT + t0 + tc*8] = a;
      *(u16x8*)&xwT[(size_t)(ch0+ch)*NT + t0 + tc*8] = wv2;
    } else {
      *(u16x8*)&BT[(size_t)(ch0 - DIN + ch)*NT + t0 + tc*8] = v;
    }
  }
}

// ---------------- chunk states + recurrence, fused ----------------
__global__ __launch_bounds__(256)
void chunk_states_fused(const __hip_bfloat16* __restrict__ xwT, const __hip_bfloat16* __restrict__ BT,
                        const float* __restrict__ Acs, __hip_bfloat16* __restrict__ states_bf) {
  int h = blockIdx.x, b = blockIdx.y;
  int g = h >> 4;
  int tid = threadIdx.x, lane = tid & 63, w = tid >> 6;
  int l15 = lane & 15, l4 = lane >> 4;
  int n0 = w*32;
  f32x4 S[4][2] = {};
  for (int c = 0; c < NC; ++c) {
    int tbase = b*SEQ + c*CS;
    const __hip_bfloat16* xp = xwT + (size_t)(h*64 + l15)*NT + tbase + l4*8;
    const __hip_bfloat16* bp = BT + (size_t)(g*128 + n0 + l15)*NT + tbase + l4*8;
    f32x4 acc[4][2] = {};
    for (int kc = 0; kc < 8; ++kc) {
      bf16x8 xf[4], bf2[2];
      #pragma unroll
      for (int tm=0;tm<4;++tm) xf[tm] = ld8bf(xp + (size_t)(tm*16)*NT + kc*32);
      #pragma unroll
      for (int tn=0;tn<2;++tn) bf2[tn] = ld8bf(bp + (size_t)(tn*16)*NT + kc*32);
      #pragma unroll
      for (int tm=0;tm<4;++tm)
        #pragma unroll
        for (int tn=0;tn<2;++tn)
          acc[tm][tn] = __builtin_amdgcn_mfma_f32_16x16x32_bf16(xf[tm], bf2[tn], acc[tm][tn], 0, 0, 0);
    }
    __hip_bfloat16* out = states_bf + ((size_t)(b*NC + c)*NH + h)*(HD*NSTATE);
    float decay = expf(Acs[((size_t)(b*NH+h)*NC + c)*CS + CS-1]);
    #pragma unroll
    for (int tm=0;tm<4;++tm)
      #pragma unroll
      for (int tn=0;tn<2;++tn)
        #pragma unroll
        for (int q=0;q<4;++q) {
          out[(size_t)(tm*16 + l4*4 + q)*NSTATE + n0 + tn*16 + l15] = __float2bfloat16(S[tm][tn][q]);
          S[tm][tn][q] = S[tm][tn][q]*decay + acc[tm][tn][q];
        }
  }
}

// ---------------- Y via MFMA (wave-causal) ----------------
__global__ __launch_bounds__(256)
void y_mfma_kernel(const __hip_bfloat16* __restrict__ zx,
                   const __hip_bfloat16* __restrict__ Cn,
                   const __hip_bfloat16* __restrict__ Bn,
                   const __hip_bfloat16* __restrict__ xsT,
                   const __hip_bfloat16* __restrict__ Sbf,
                   const float* __restrict__ dt_sp,
                   const float* __restrict__ Acs,
                   const float* __restrict__ Dp,
                   __hip_bfloat16* __restrict__ ybf) {
  int h = blockIdx.x;
  int bc = blockIdx.y;
  int c = bc & 7, b = bc >> 3;
  int g = h >> 4;
  int tbase = b*SEQ + c*CS;
  int tid = threadIdx.x, lane = tid & 63, w = tid >> 6;
  int l15 = lane & 15, l4 = lane >> 4;
  int i0 = w*64;
  __shared__ float acs_s[CS];
  __shared__ unsigned short P[4][64][72];
  acs_s[tid] = Acs[((size_t)(b*NH+h)*NC + c)*CS + tid];
  __syncthreads();

  float acs_i[4], rd[4];
  float Dh = Dp[h];
  #pragma unroll
  for (int ti=0;ti<4;++ti) {
    int ig = i0 + ti*16 + l15;
    acs_i[ti] = acs_s[ig];
    rd[ti] = Dh / dt_sp[(size_t)(tbase+ig)*NH + h];
  }
  const __hip_bfloat16* Cbase = Cn + (size_t)tbase*1024 + g*128;
  const __hip_bfloat16* Bbase = Bn + (size_t)tbase*1024 + g*128;
  const __hip_bfloat16* xbase = xsT + (size_t)(h*64 + l15)*NT + tbase;

  f32x4 accY[4][4] = {};
  for (int jb = 0; jb <= w; ++jb) {
    int j0 = jb*64;
    f32x4 sacc[4][4] = {};
    for (int kc = 0; kc < 4; ++kc) {
      bf16x8 bfr[4], cfr[4];
      #pragma unroll
      for (int tj=0;tj<4;++tj) bfr[tj] = ld8bf(Bbase + (size_t)(j0 + tj*16 + l15)*1024 + kc*32 + l4*8);
      #pragma unroll
      for (int ti=0;ti<4;++ti) cfr[ti] = ld8bf(Cbase + (size_t)(i0 + ti*16 + l15)*1024 + kc*32 + l4*8);
      #pragma unroll
      for (int tj=0;tj<4;++tj)
        #pragma unroll
        for (int ti=0;ti<4;++ti)
          sacc[tj][ti] = __builtin_amdgcn_mfma_f32_16x16x32_bf16(bfr[tj], cfr[ti], sacc[tj][ti], 0, 0, 0);
    }
    #pragma unroll
    for (int tj=0;tj<4;++tj)
      #pragma unroll
      for (int ti=0;ti<4;++ti) {
        int ig = i0 + ti*16 + l15;
        float ai = acs_i[ti];
        u16x4 pk;
        #pragma unroll
        for (int q=0;q<4;++q) {
          int jg = j0 + tj*16 + l4*4 + q;
          float v = (jg <= ig) ? sacc[tj][ti][q] * __expf(ai - acs_s[jg]) : 0.f;
          if (jg == ig) v += rd[ti];
          pk[q] = f2b(v);
        }
        *(u16x4*)&P[w][ti*16 + l15][tj*16 + l4*4] = pk;
      }
    #pragma unroll
    for (int kc2 = 0; kc2 < 2; ++kc2) {
      bf16x8 xf[4], pf[4];
      #pragma unroll
      for (int tm=0;tm<4;++tm) xf[tm] = ld8bf(xbase + (size_t)(tm*16)*NT + j0 + kc2*32 + l4*8);
      #pragma unroll
      for (int ti=0;ti<4;++ti) pf[ti] = *(const bf16x8*)&P[w][ti*16 + l15][kc2*32 + l4*8];
      #pragma unroll
      for (int tm=0;tm<4;++tm)
        #pragma unroll
        for (int ti=0;ti<4;++ti)
          accY[tm][ti] = __builtin_amdgcn_mfma_f32_16x16x32_bf16(xf[tm], pf[ti], accY[tm][ti], 0, 0, 0);
    }
  }
  const __hip_bfloat16* Sb = Sbf + ((size_t)bc*NH + h)*(HD*NSTATE);
  f32x4 oacc[4][4] = {};
  for (int kc = 0; kc < 4; ++kc) {
    bf16x8 sf[4], cfr[4];
    #pragma unroll
    for (int tm=0;tm<4;++tm) sf[tm] = ld8bf(Sb + (size_t)(tm*16 + l15)*NSTATE + kc*32 + l4*8);
    #pragma unroll
    for (int ti=0;ti<4;++ti) cfr[ti] = ld8bf(Cbase + (size_t)(i0 + ti*16 + l15)*1024 + kc*32 + l4*8);
    #pragma unroll
    for (int tm=0;tm<4;++tm)
      #pragma unroll
      for (int ti=0;ti<4;++ti)
        oacc[tm][ti] = __builtin_amdgcn_mfma_f32_16x16x32_bf16(sf[tm], cfr[ti], oacc[tm][ti], 0, 0, 0);
  }
  #pragma unroll
  for (int ti=0;ti<4;++ti) {
    int ig = i0 + ti*16 + l15;
    int t = tbase + ig;
    float sd = __expf(acs_i[ti]);
    #pragma unroll
    for (int tm=0;tm<4;++tm) {
      int ch0 = h*64 + tm*16 + l4*4;
      u16x4 gv = *(const u16x4*)&zx[(size_t)t*ZXW + ch0];
      u16x4 out;
      #pragma unroll
      for (int q=0;q<4;++q) {
        float yv = accY[tm][ti][q] + sd * oacc[tm][ti][q];
        yv *= siluf_(b2f(gv[q]));
        out[q] = f2b(yv);
      }
      *(u16x4*)&ybf[(size_t)t*DIN + ch0] = out;
    }
  }
}

// ---------------- RMS groupnorm, bf16 in-place ----------------
__global__ __launch_bounds__(256)
void groupnorm_bf16_kernel(unsigned short* __restrict__ y, const float* __restrict__ norm_w) {
  int bid = blockIdx.x;
  int g = bid % G;
  int t = bid / G;
  unsigned short* yp = y + (size_t)t*DIN + g*GROUP_SIZE;
  int tid = threadIdx.x;
  u16x4 v = *(const u16x4*)&yp[tid*4];
  float f[4]; float ss = 0.f;
  #pragma unroll
  for (int j=0;j<4;++j) { f[j] = b2f(v[j]); ss += f[j]*f[j]; }
  #pragma unroll
  for (int off = 32; off > 0; off >>= 1) ss += __shfl_xor(ss, off);
  __shared__ float wsum[4];
  int wave = tid >> 6;
  if ((tid & 63) == 0) wsum[wave] = ss;
  __syncthreads();
  float tot = wsum[0]+wsum[1]+wsum[2]+wsum[3];
  float rs = rsqrtf(tot/(float)GROUP_SIZE + 1e-5f);
  const float* nw = norm_w + g*GROUP_SIZE + tid*4;
  u16x4 o;
  #pragma unroll
  for (int j=0;j<4;++j) o[j] = f2b(f[j] * rs * nw[j]);
  *(u16x4*)&yp[tid*4] = o;
}

extern "C" void kernel_launch(void* const* d_in, const int* in_sizes, int n_in,
                              void* d_out, int out_size, void* d_ws, size_t ws_size,
                              hipStream_t stream) {
  const float* hs        = (const float*)d_in[0];
  const float* in_proj_w = (const float*)d_in[1];
  const float* conv_w    = (const float*)d_in[2];
  const float* conv_b    = (const float*)d_in[3];
  const float* dt_bias   = (const float*)d_in[4];
  const float* A_log     = (const float*)d_in[5];
  const float* Dp        = (const float*)d_in[6];
  const float* norm_w    = (const float*)d_in[7];
  const float* out_proj_w= (const float*)d_in[8];
  float* outp = (float*)d_out;

  char* ws = (char*)d_ws;
  __hip_bfloat16* zx_bf = (__hip_bfloat16*)ws;                      // NT*ZXW*2 = 150,994,944
  char* p = ws + (size_t)NT*ZXW*2;
  __hip_bfloat16* B_bf  = (__hip_bfloat16*)p; p += (size_t)NT*G*NSTATE*2;
  __hip_bfloat16* C_bf  = (__hip_bfloat16*)p; p += (size_t)NT*G*NSTATE*2;
  __hip_bfloat16* BT    = (__hip_bfloat16*)p; p += (size_t)NT*G*NSTATE*2;
  __hip_bfloat16* y_bf  = (__hip_bfloat16*)p; p += (size_t)NT*DIN*2;
  float* dtb    = (float*)p;  p += (size_t)NT*NH*4;
  float* Acs    = (float*)p;  p += (size_t)BATCH*NH*NC*CS*4;
  float* dt_part = (float*)y_bf;     // aliases y_bf (dead until y_mfma)
  char* F = p;
  __hip_bfloat16* w_in_bf   = (__hip_bfloat16*)F;
  __hip_bfloat16* xsT       = (__hip_bfloat16*)F;
  __hip_bfloat16* xwT       = (__hip_bfloat16*)(F + 67108864);
  __hip_bfloat16* hs_bf     = (__hip_bfloat16*)(F + 150994944);
  __hip_bfloat16* states_bf = (__hip_bfloat16*)(F + 150994944);
  char* F2 = F + 150994944 + 33554432;
  __hip_bfloat16* w_out_bf  = (__hip_bfloat16*)F2;

  dt_gemm_splitk<<<dim3(DTSK, NT/128), 256, 0, stream>>>(hs, in_proj_w + (size_t)ZXW*HID, dt_part, hs_bf);
  dt_scan_kernel<<<BATCH*NH*NC, CS, 0, stream>>>(dt_part, dt_bias, A_log, dtb, Acs);

  cast2_kernel<<<4096, 256, 0, stream>>>(in_proj_w, w_in_bf, out_proj_w, w_out_bf);

  gemm_bf16_256<true><<<dim3((NT/256)*(ZXW/256)), 512, 0, stream>>>(
      hs_bf, w_in_bf, zx_bf, NT, ZXW, HID);

  conv_fused_kernel<<<dim3(NT/64, CONV_DIM/64), 256, 0, stream>>>(
      zx_bf, conv_w, conv_b, dtb, Acs, xsT, xwT, B_bf, C_bf, BT);

  chunk_states_fused<<<dim3(NH, BATCH), 256, 0, stream>>>(xwT, BT, Acs, states_bf);

  y_mfma_kernel<<<dim3(NH, BATCH*NC), 256, 0, stream>>>(zx_bf, C_bf, B_bf, xsT, states_bf, dtb, Acs, Dp, y_bf);
  groupnorm_bf16_kernel<<<NT*G, 256, 0, stream>>>((unsigned short*)y_bf, norm_w);

  gemm_bf16_256<false><<<dim3((NT/256)*(HID/256)), 512, 0, stream>>>(
      y_bf, w_out_bf, outp, NT, HID, DIN);
}

// Round 15
// 1729.365 us; speedup vs baseline: 1.1298x; 1.0309x over previous
//
#include <hip/hip_runtime.h>
#include <hip/hip_bf16.h>
#include <math.h>

#define HID 4096
#define NH 128
#define HD 64
#define DIN 8192      // NH*HD
#define G 8
#define NSTATE 128
#define CS 256
#define GROUP_SIZE 1024
#define CONV_DIM 10240  // DIN + 2*G*NSTATE
#define ZXW 18432       // DIN + CONV_DIM = 72*256 (dt columns handled by fp32 path)
#define BATCH 2
#define SEQ 2048
#define NT (BATCH*SEQ)  // 4096 tokens
#define NC 8            // SEQ/CS
#define DTSK 16         // split-K factor for the fp32 dt GEMM

typedef __attribute__((ext_vector_type(8))) short bf16x8;
typedef __attribute__((ext_vector_type(4))) float f32x4;
typedef __attribute__((ext_vector_type(8))) unsigned short u16x8;
typedef __attribute__((ext_vector_type(4))) unsigned short u16x4;

__device__ __forceinline__ float sigmoidf_(float x){ return 1.f/(1.f+expf(-x)); }
__device__ __forceinline__ float siluf_(float x){ return x*sigmoidf_(x); }
__device__ __forceinline__ float softplusf_(float x){ return (x>20.f)? x : log1pf(expf(x)); }
__device__ __forceinline__ float b2f(unsigned short u){ union{unsigned int i; float f;} x; x.i = ((unsigned int)u)<<16; return x.f; }
__device__ __forceinline__ unsigned short f2b(float f){ __hip_bfloat16 h = __float2bfloat16(f); return *(unsigned short*)&h; }

__device__ __forceinline__ void gload_lds16(const void* g, void* l) {
  __builtin_amdgcn_global_load_lds((const __attribute__((address_space(1))) unsigned int*)g,
                                   (__attribute__((address_space(3))) unsigned int*)l, 16, 0, 0);
}
__device__ __forceinline__ bf16x8 ld8bf(const __hip_bfloat16* p){ return *(const bf16x8*)p; }

__device__ __forceinline__ void cast8(const float* in, __hip_bfloat16* out) {
  const float4* p = (const float4*)in;
  float4 a = p[0], b = p[1];
  union { __hip_bfloat16 h[8]; int4 v; } o;
  o.h[0]=__float2bfloat16(a.x); o.h[1]=__float2bfloat16(a.y);
  o.h[2]=__float2bfloat16(a.z); o.h[3]=__float2bfloat16(a.w);
  o.h[4]=__float2bfloat16(b.x); o.h[5]=__float2bfloat16(b.y);
  o.h[6]=__float2bfloat16(b.z); o.h[7]=__float2bfloat16(b.w);
  *(int4*)out = o.v;
}

// ---------------- weight fp32->bf16 casts (hs handled by dt_gemm) ----------------
__global__ __launch_bounds__(256)
void cast2_kernel(const float* __restrict__ w_in, __hip_bfloat16* __restrict__ w_in_bf,
                  const float* __restrict__ w_out, __hip_bfloat16* __restrict__ w_out_bf) {
  const size_t n1 = (size_t)ZXW*HID/8;
  const size_t n2 = (size_t)HID*DIN/8;
  const size_t ntot = n1 + n2;
  size_t i = (size_t)blockIdx.x * 256 + threadIdx.x;
  size_t stride = (size_t)gridDim.x * 256;
  for (; i < ntot; i += stride) {
    if (i < n1)  cast8(w_in + i*8,      w_in_bf + i*8);
    else         cast8(w_out+ (i-n1)*8, w_out_bf+ (i-n1)*8);
  }
}

// ---------------- 256x256 bf16 MFMA GEMM, 2-phase interleave, counted vmcnt ----------------
// (round-8 version: best measured; LDS-throughput-bound at ~36% MfmaUtil, conflicts 0)
template<bool OUT_BF16>
__global__ __launch_bounds__(512)
void gemm_bf16_256(const __hip_bfloat16* __restrict__ A, const __hip_bfloat16* __restrict__ B,
                   void* __restrict__ Cout, int M, int N, int K) {
  const int nMt = M >> 8, nNt = N >> 8;
  const int nwg = nMt * nNt;
  const int cpx = nwg >> 3;
  const int lin = blockIdx.x;
  const int swz = (lin & 7) * cpx + (lin >> 3);   // XCD-chunked (nwg%8==0)
  const int mt = swz % nMt, ntile = swz / nMt;    // M fastest -> B panel L2-hot
  const int rowBase = mt << 8;
  const int colBase = ntile << 8;

  __shared__ short As[4][8192];   // 4 x 16KB
  __shared__ short Bs[4][8192];

  const int tid = threadIdx.x;
  const int lane = tid & 63, wid = tid >> 6;
  const int wr = wid >> 2, wc = wid & 3;          // 2M x 4N wave grid
  const int l15 = lane & 15, l4 = lane >> 4;

  const int r0 = tid >> 2,        c0 = (tid & 3) ^ ((r0 >> 1) & 3);
  const int r1 = (512+tid) >> 2,  c1 = ((512+tid) & 3) ^ ((r1 >> 1) & 3);
  const __hip_bfloat16* gA0 = A + (size_t)(rowBase + r0)*K + c0*8;
  const __hip_bfloat16* gA1 = A + (size_t)(rowBase + r1)*K + c1*8;
  const __hip_bfloat16* gB0 = B + (size_t)(colBase + r0)*K + c0*8;
  const __hip_bfloat16* gB1 = B + (size_t)(colBase + r1)*K + c1*8;
  const int ld0 = wid*512, ld1 = 4096 + wid*512;

#define STAGE_A(q, kt) do { \
    gload_lds16(gA0 + (size_t)(kt)*32, (void*)&As[q][ld0]); \
    gload_lds16(gA1 + (size_t)(kt)*32, (void*)&As[q][ld1]); \
  } while(0)
#define STAGE_B(q, kt) do { \
    gload_lds16(gB0 + (size_t)(kt)*32, (void*)&Bs[q][ld0]); \
    gload_lds16(gB1 + (size_t)(kt)*32, (void*)&Bs[q][ld1]); \
  } while(0)

  int aoff[8], boff[4];
  #pragma unroll
  for (int m=0;m<8;++m){ int r = wr*128 + m*16 + l15; aoff[m] = r*32 + ((l4 ^ ((r>>1)&3))*8); }
  #pragma unroll
  for (int n=0;n<4;++n){ int r = wc*64  + n*16 + l15; boff[n] = r*32 + ((l4 ^ ((r>>1)&3))*8); }

  f32x4 acc[8][4] = {};
  const int NKT = K >> 5;

  STAGE_A(0,0); STAGE_B(0,0);
  STAGE_A(1,1); STAGE_B(1,1);
  STAGE_A(2,2); STAGE_B(2,2);
  asm volatile("s_waitcnt vmcnt(8)" ::: "memory");
  __builtin_amdgcn_s_barrier();

  for (int t = 0; t < NKT; ++t) {
    const short* ab = &As[t&3][0];
    const short* bb = &Bs[t&3][0];
    const int q3 = (t+3)&3;
    bf16x8 a[4], b[4], a2[4];
    // phase A
    #pragma unroll
    for (int m=0;m<4;++m) a[m] = *(const bf16x8*)&ab[aoff[m]];
    #pragma unroll
    for (int n=0;n<4;++n) b[n] = *(const bf16x8*)&bb[boff[n]];
    if (t + 3 < NKT) STAGE_A(q3, t+3);
    __builtin_amdgcn_s_barrier();
    asm volatile("s_waitcnt lgkmcnt(0)" ::: "memory");
    __builtin_amdgcn_sched_barrier(0);
    __builtin_amdgcn_s_setprio(1);
    #pragma unroll
    for (int m=0;m<4;++m)
      #pragma unroll
      for (int n=0;n<4;++n)
        acc[m][n] = __builtin_amdgcn_mfma_f32_16x16x32_bf16(a[m], b[n], acc[m][n], 0, 0, 0);
    __builtin_amdgcn_s_setprio(0);
    __builtin_amdgcn_s_barrier();
    // phase B
    #pragma unroll
    for (int m=0;m<4;++m) a2[m] = *(const bf16x8*)&ab[aoff[m+4]];
    if (t + 3 < NKT) STAGE_B(q3, t+3);
    const int rem = NKT - 1 - t;
    if (rem >= 3)      asm volatile("s_waitcnt vmcnt(8)" ::: "memory");
    else if (rem == 2) asm volatile("s_waitcnt vmcnt(4)" ::: "memory");
    else if (rem == 1) asm volatile("s_waitcnt vmcnt(0)" ::: "memory");
    __builtin_amdgcn_s_barrier();
    asm volatile("s_waitcnt lgkmcnt(0)" ::: "memory");
    __builtin_amdgcn_sched_barrier(0);
    __builtin_amdgcn_s_setprio(1);
    #pragma unroll
    for (int m=0;m<4;++m)
      #pragma unroll
      for (int n=0;n<4;++n)
        acc[m+4][n] = __builtin_amdgcn_mfma_f32_16x16x32_bf16(a2[m], b[n], acc[m+4][n], 0, 0, 0);
    __builtin_amdgcn_s_setprio(0);
    __builtin_amdgcn_s_barrier();
  }
#undef STAGE_A
#undef STAGE_B

  #pragma unroll
  for (int m=0;m<8;++m) {
    int row0 = rowBase + wr*128 + m*16 + l4*4;
    #pragma unroll
    for (int n=0;n<4;++n) {
      int col = colBase + wc*64 + n*16 + l15;
      #pragma unroll
      for (int j=0;j<4;++j) {
        if (OUT_BF16)
          ((__hip_bfloat16*)Cout)[(size_t)(row0+j)*N + col] = __float2bfloat16(acc[m][n][j]);
        else
          ((float*)Cout)[(size_t)(row0+j)*N + col] = acc[m][n][j];
      }
    }
  }
}

// ---------------- fp32 dt GEMM, split-K; also emits hs_bf ----------------
__global__ __launch_bounds__(256)
void dt_gemm_splitk(const float* __restrict__ A, const float* __restrict__ B,
                    float* __restrict__ partial, __hip_bfloat16* __restrict__ hs_bf) {
  __shared__ float As[16][132];
  __shared__ float Bs[16][132];
  const int tid = threadIdx.x;
  const int tx = tid & 15, ty = tid >> 4;
  const int rowBase = blockIdx.y * 128;
  const int k0 = blockIdx.x * (HID/DTSK);
  float acc[8][8] = {};
  for (int kt = k0; kt < k0 + HID/DTSK; kt += 16) {
    for (int e = tid; e < 128*16; e += 256) {
      int r = e >> 4, c = e & 15;
      float av = A[(size_t)(rowBase + r) * HID + kt + c];
      As[c][r] = av;
      hs_bf[(size_t)(rowBase + r) * HID + kt + c] = __float2bfloat16(av);
      Bs[c][r] = B[(size_t)r * HID + kt + c];
    }
    __syncthreads();
    #pragma unroll
    for (int kk = 0; kk < 16; ++kk) {
      float a[8], bv[8];
      #pragma unroll
      for (int i = 0; i < 8; ++i) a[i] = As[kk][ty*8+i];
      #pragma unroll
      for (int j = 0; j < 8; ++j) bv[j] = Bs[kk][tx*8+j];
      #pragma unroll
      for (int i = 0; i < 8; ++i)
        #pragma unroll
        for (int j = 0; j < 8; ++j)
          acc[i][j] += a[i]*bv[j];
    }
    __syncthreads();
  }
  float* outp = partial + (size_t)blockIdx.x * NT * NH;
  for (int i = 0; i < 8; ++i) {
    size_t ro = (size_t)(rowBase + ty*8 + i) * NH + tx*8;
    #pragma unroll
    for (int j = 0; j < 8; ++j) outp[ro + j] = acc[i][j];
  }
}

// ---------------- dt: split-K reduce + softplus + per-chunk cumsum ----------------
__global__ __launch_bounds__(256)
void dt_scan_kernel(const float* __restrict__ partial, const float* __restrict__ dt_bias,
                    const float* __restrict__ A_log, float* __restrict__ dt_sp,
                    float* __restrict__ Acs) {
  int bid = blockIdx.x;       // (b*NH + h)*NC + c
  int c = bid % NC;
  int h = (bid / NC) % NH;
  int b = bid / (NC*NH);
  int k = threadIdx.x;
  int t = b*SEQ + c*CS + k;
  float raw = dt_bias[h];
  #pragma unroll
  for (int sk = 0; sk < DTSK; ++sk) raw += partial[(size_t)sk*NT*NH + (size_t)t*NH + h];
  float dtv = softplusf_(raw);
  dt_sp[(size_t)t*NH + h] = dtv;
  float adt = -expf(A_log[h]) * dtv;
  __shared__ float s[CS];
  s[k] = adt;
  __syncthreads();
  for (int off = 1; off < CS; off <<= 1) {
    float v = (k >= off) ? s[k-off] : 0.f;
    __syncthreads();
    s[k] += v;
    __syncthreads();
  }
  Acs[((size_t)(b*NH + h)*NC + c)*CS + k] = s[k];
}

// ---------------- fused conv+SiLU + transpose + dt scaling ----------------
__global__ __launch_bounds__(256)
void conv_fused_kernel(const __hip_bfloat16* __restrict__ zx, const float* __restrict__ w,
                       const float* __restrict__ bias,
                       const float* __restrict__ dt_sp, const float* __restrict__ Acs,
                       __hip_bfloat16* __restrict__ xsT, __hip_bfloat16* __restrict__ xwT,
                       __hip_bfloat16* __restrict__ Bbf, __hip_bfloat16* __restrict__ Cbf,
                       __hip_bfloat16* __restrict__ BT) {
  const int tt = blockIdx.x;
  const int ct = blockIdx.y;
  const int t0 = tt*64;
  const int ch0 = ct*64;
  const int tid = threadIdx.x;
  __shared__ unsigned short T[64][72];
  __shared__ float dts[64], ews[64];

  const bool isX = (ch0 < DIN);
  const bool isB = (ch0 >= DIN) && (ch0 < DIN + G*NSTATE);

  if (isX && tid < 64) {
    int h = ch0 >> 6;
    int t = t0 + tid;
    dts[tid] = dt_sp[(size_t)t*NH + h];
    int b = t0 >> 11, cc = (t0 >> 8) & 7, k0 = t0 & 255;
    const float* acs = Acs + ((size_t)(b*NH+h)*NC + cc)*CS;
    ews[tid] = __expf(acs[CS-1] - acs[k0 + tid]);
  }

  const int l0 = t0 & (SEQ-1);
  #pragma unroll
  for (int it = 0; it < 2; ++it) {
    int r = tid >> 2;
    int c8 = (tid & 3) + it*4;
    int cb = ch0 + c8*8;
    float acc[8];
    *(float4*)&acc[0] = *(const float4*)&bias[cb];
    *(float4*)&acc[4] = *(const float4*)&bias[cb+4];
    float4 wv[8];
    #pragma unroll
    for (int q=0;q<8;++q) wv[q] = *(const float4*)&w[(cb+q)*4];
    #pragma unroll
    for (int k=0;k<4;++k) {
      if (l0 + r - 3 + k >= 0) {
        u16x8 v = *(const u16x8*)&zx[(size_t)(t0+r-3+k)*ZXW + DIN + cb];
        #pragma unroll
        for (int q=0;q<8;++q) acc[q] += b2f(v[q]) * ((const float*)&wv[q])[k];
      }
    }
    u16x8 o;
    #pragma unroll
    for (int q=0;q<8;++q) o[q] = f2b(siluf_(acc[q]));
    if (isX || isB) {
      #pragma unroll
      for (int q=0;q<8;++q) T[c8*8+q][r] = o[q];
    }
    if (!isX) {
      if (isB) *(u16x8*)&Bbf[(size_t)(t0+r)*(G*NSTATE) + (cb - DIN)] = o;
      else     *(u16x8*)&Cbf[(size_t)(t0+r)*(G*NSTATE) + (cb - DIN - G*NSTATE)] = o;
    }
  }
  if (!isX && !isB) return;
  __syncthreads();
  #pragma unroll
  for (int it = 0; it < 2; ++it) {
    int ch = tid >> 2;
    int tc = (tid & 3) + it*4;
    u16x8 v = *(const u16x8*)&T[ch][tc*8];
    if (isX) {
      u16x8 a, wv2;
      #pragma unroll
      for (int q=0;q<8;++q) {
        float f = b2f(v[q]);
        float fs = f * dts[tc*8+q];
        a[q]   = f2b(fs);
        wv2[q] = f2b(fs * ews[tc*8+q]);
      }
      *(u16x8*)&xsT[(size_t)(ch0+ch)*NT + t0 + tc*8] = a;
      *(u16x8*)&xwT[(size_t)(ch0+ch)*NT + t0 + tc*8] = wv2;
    } else {
      *(u16x8*)&BT[(size_t)(ch0 - DIN + ch)*NT + t0 + tc*8] = v;
    }
  }
}

// ---------------- chunk states + recurrence, fused ----------------
__global__ __launch_bounds__(256)
void chunk_states_fused(const __hip_bfloat16* __restrict__ xwT, const __hip_bfloat16* __restrict__ BT,
                        const float* __restrict__ Acs, __hip_bfloat16* __restrict__ states_bf) {
  int h = blockIdx.x, b = blockIdx.y;
  int g = h >> 4;
  int tid = threadIdx.x, lane = tid & 63, w = tid >> 6;
  int l15 = lane & 15, l4 = lane >> 4;
  int n0 = w*32;
  f32x4 S[4][2] = {};
  for (int c = 0; c < NC; ++c) {
    int tbase = b*SEQ + c*CS;
    const __hip_bfloat16* xp = xwT + (size_t)(h*64 + l15)*NT + tbase + l4*8;
    const __hip_bfloat16* bp = BT + (size_t)(g*128 + n0 + l15)*NT + tbase + l4*8;
    f32x4 acc[4][2] = {};
    for (int kc = 0; kc < 8; ++kc) {
      bf16x8 xf[4], bf2[2];
      #pragma unroll
      for (int tm=0;tm<4;++tm) xf[tm] = ld8bf(xp + (size_t)(tm*16)*NT + kc*32);
      #pragma unroll
      for (int tn=0;tn<2;++tn) bf2[tn] = ld8bf(bp + (size_t)(tn*16)*NT + kc*32);
      #pragma unroll
      for (int tm=0;tm<4;++tm)
        #pragma unroll
        for (int tn=0;tn<2;++tn)
          acc[tm][tn] = __builtin_amdgcn_mfma_f32_16x16x32_bf16(xf[tm], bf2[tn], acc[tm][tn], 0, 0, 0);
    }
    __hip_bfloat16* out = states_bf + ((size_t)(b*NC + c)*NH + h)*(HD*NSTATE);
    float decay = expf(Acs[((size_t)(b*NH+h)*NC + c)*CS + CS-1]);
    #pragma unroll
    for (int tm=0;tm<4;++tm)
      #pragma unroll
      for (int tn=0;tn<2;++tn)
        #pragma unroll
        for (int q=0;q<4;++q) {
          out[(size_t)(tm*16 + l4*4 + q)*NSTATE + n0 + tn*16 + l15] = __float2bfloat16(S[tm][tn][q]);
          S[tm][tn][q] = S[tm][tn][q]*decay + acc[tm][tn][q];
        }
  }
}

// ---------------- Y via MFMA (wave-causal; hoisted C-frags; off-diag fast path) ----------------
__global__ __launch_bounds__(256)
void y_mfma_kernel(const __hip_bfloat16* __restrict__ zx,
                   const __hip_bfloat16* __restrict__ Cn,
                   const __hip_bfloat16* __restrict__ Bn,
                   const __hip_bfloat16* __restrict__ xsT,
                   const __hip_bfloat16* __restrict__ Sbf,
                   const float* __restrict__ dt_sp,
                   const float* __restrict__ Acs,
                   const float* __restrict__ Dp,
                   __hip_bfloat16* __restrict__ ybf) {
  int h = blockIdx.x;
  int bc = blockIdx.y;
  int c = bc & 7, b = bc >> 3;
  int g = h >> 4;
  int tbase = b*SEQ + c*CS;
  int tid = threadIdx.x, lane = tid & 63, w = tid >> 6;
  int l15 = lane & 15, l4 = lane >> 4;
  int i0 = w*64;
  __shared__ float acs_s[CS];
  __shared__ unsigned short P[4][64][72];
  acs_s[tid] = Acs[((size_t)(b*NH+h)*NC + c)*CS + tid];
  __syncthreads();

  float acs_i[4], rd[4];
  float Dh = Dp[h];
  #pragma unroll
  for (int ti=0;ti<4;++ti) {
    int ig = i0 + ti*16 + l15;
    acs_i[ti] = acs_s[ig];
    rd[ti] = Dh / dt_sp[(size_t)(tbase+ig)*NH + h];
  }
  const __hip_bfloat16* Cbase = Cn + (size_t)tbase*1024 + g*128;
  const __hip_bfloat16* Bbase = Bn + (size_t)tbase*1024 + g*128;
  const __hip_bfloat16* xbase = xsT + (size_t)(h*64 + l15)*NT + tbase;

  // hoisted C fragments: depend only on (i0, kc) -> load once, reuse in all jb and Y_off
  bf16x8 cfr[4][4];   // [kc][ti]
  #pragma unroll
  for (int kc = 0; kc < 4; ++kc)
    #pragma unroll
    for (int ti=0;ti<4;++ti)
      cfr[kc][ti] = ld8bf(Cbase + (size_t)(i0 + ti*16 + l15)*1024 + kc*32 + l4*8);

  f32x4 accY[4][4] = {};
  for (int jb = 0; jb <= w; ++jb) {
    int j0 = jb*64;
    f32x4 sacc[4][4] = {};
    for (int kc = 0; kc < 4; ++kc) {
      bf16x8 bfr[4];
      #pragma unroll
      for (int tj=0;tj<4;++tj) bfr[tj] = ld8bf(Bbase + (size_t)(j0 + tj*16 + l15)*1024 + kc*32 + l4*8);
      #pragma unroll
      for (int tj=0;tj<4;++tj)
        #pragma unroll
        for (int ti=0;ti<4;++ti)
          sacc[tj][ti] = __builtin_amdgcn_mfma_f32_16x16x32_bf16(bfr[tj], cfr[kc][ti], sacc[tj][ti], 0, 0, 0);
    }
    if (jb < w) {
      // fully causal quadrant: no mask, no diagonal residual
      #pragma unroll
      for (int tj=0;tj<4;++tj)
        #pragma unroll
        for (int ti=0;ti<4;++ti) {
          float ai = acs_i[ti];
          u16x4 pk;
          #pragma unroll
          for (int q=0;q<4;++q) {
            int jg = j0 + tj*16 + l4*4 + q;
            pk[q] = f2b(sacc[tj][ti][q] * __expf(ai - acs_s[jg]));
          }
          *(u16x4*)&P[w][ti*16 + l15][tj*16 + l4*4] = pk;
        }
    } else {
      #pragma unroll
      for (int tj=0;tj<4;++tj)
        #pragma unroll
        for (int ti=0;ti<4;++ti) {
          int ig = i0 + ti*16 + l15;
          float ai = acs_i[ti];
          u16x4 pk;
          #pragma unroll
          for (int q=0;q<4;++q) {
            int jg = j0 + tj*16 + l4*4 + q;
            float v = (jg <= ig) ? sacc[tj][ti][q] * __expf(ai - acs_s[jg]) : 0.f;
            if (jg == ig) v += rd[ti];
            pk[q] = f2b(v);
          }
          *(u16x4*)&P[w][ti*16 + l15][tj*16 + l4*4] = pk;
        }
    }
    #pragma unroll
    for (int kc2 = 0; kc2 < 2; ++kc2) {
      bf16x8 xf[4], pf[4];
      #pragma unroll
      for (int tm=0;tm<4;++tm) xf[tm] = ld8bf(xbase + (size_t)(tm*16)*NT + j0 + kc2*32 + l4*8);
      #pragma unroll
      for (int ti=0;ti<4;++ti) pf[ti] = *(const bf16x8*)&P[w][ti*16 + l15][kc2*32 + l4*8];
      #pragma unroll
      for (int tm=0;tm<4;++tm)
        #pragma unroll
        for (int ti=0;ti<4;++ti)
          accY[tm][ti] = __builtin_amdgcn_mfma_f32_16x16x32_bf16(xf[tm], pf[ti], accY[tm][ti], 0, 0, 0);
    }
  }
  // Y_off: reuse hoisted cfr
  const __hip_bfloat16* Sb = Sbf + ((size_t)bc*NH + h)*(HD*NSTATE);
  f32x4 oacc[4][4] = {};
  #pragma unroll
  for (int kc = 0; kc < 4; ++kc) {
    bf16x8 sf[4];
    #pragma unroll
    for (int tm=0;tm<4;++tm) sf[tm] = ld8bf(Sb + (size_t)(tm*16 + l15)*NSTATE + kc*32 + l4*8);
    #pragma unroll
    for (int tm=0;tm<4;++tm)
      #pragma unroll
      for (int ti=0;ti<4;++ti)
        oacc[tm][ti] = __builtin_amdgcn_mfma_f32_16x16x32_bf16(sf[tm], cfr[kc][ti], oacc[tm][ti], 0, 0, 0);
  }
  #pragma unroll
  for (int ti=0;ti<4;++ti) {
    int ig = i0 + ti*16 + l15;
    int t = tbase + ig;
    float sd = __expf(acs_i[ti]);
    #pragma unroll
    for (int tm=0;tm<4;++tm) {
      int ch0 = h*64 + tm*16 + l4*4;
      u16x4 gv = *(const u16x4*)&zx[(size_t)t*ZXW + ch0];
      u16x4 out;
      #pragma unroll
      for (int q=0;q<4;++q) {
        float yv = accY[tm][ti][q] + sd * oacc[tm][ti][q];
        yv *= siluf_(b2f(gv[q]));
        out[q] = f2b(yv);
      }
      *(u16x4*)&ybf[(size_t)t*DIN + ch0] = out;
    }
  }
}

// ---------------- RMS groupnorm, bf16 in-place ----------------
__global__ __launch_bounds__(256)
void groupnorm_bf16_kernel(unsigned short* __restrict__ y, const float* __restrict__ norm_w) {
  int bid = blockIdx.x;
  int g = bid % G;
  int t = bid / G;
  unsigned short* yp = y + (size_t)t*DIN + g*GROUP_SIZE;
  int tid = threadIdx.x;
  u16x4 v = *(const u16x4*)&yp[tid*4];
  float f[4]; float ss = 0.f;
  #pragma unroll
  for (int j=0;j<4;++j) { f[j] = b2f(v[j]); ss += f[j]*f[j]; }
  #pragma unroll
  for (int off = 32; off > 0; off >>= 1) ss += __shfl_xor(ss, off);
  __shared__ float wsum[4];
  int wave = tid >> 6;
  if ((tid & 63) == 0) wsum[wave] = ss;
  __syncthreads();
  float tot = wsum[0]+wsum[1]+wsum[2]+wsum[3];
  float rs = rsqrtf(tot/(float)GROUP_SIZE + 1e-5f);
  const float* nw = norm_w + g*GROUP_SIZE + tid*4;
  u16x4 o;
  #pragma unroll
  for (int j=0;j<4;++j) o[j] = f2b(f[j] * rs * nw[j]);
  *(u16x4*)&yp[tid*4] = o;
}

extern "C" void kernel_launch(void* const* d_in, const int* in_sizes, int n_in,
                              void* d_out, int out_size, void* d_ws, size_t ws_size,
                              hipStream_t stream) {
  const float* hs        = (const float*)d_in[0];
  const float* in_proj_w = (const float*)d_in[1];
  const float* conv_w    = (const float*)d_in[2];
  const float* conv_b    = (const float*)d_in[3];
  const float* dt_bias   = (const float*)d_in[4];
  const float* A_log     = (const float*)d_in[5];
  const float* Dp        = (const float*)d_in[6];
  const float* norm_w    = (const float*)d_in[7];
  const float* out_proj_w= (const float*)d_in[8];
  float* outp = (float*)d_out;

  char* ws = (char*)d_ws;
  __hip_bfloat16* zx_bf = (__hip_bfloat16*)ws;                      // NT*ZXW*2 = 150,994,944
  char* p = ws + (size_t)NT*ZXW*2;
  __hip_bfloat16* B_bf  = (__hip_bfloat16*)p; p += (size_t)NT*G*NSTATE*2;
  __hip_bfloat16* C_bf  = (__hip_bfloat16*)p; p += (size_t)NT*G*NSTATE*2;
  __hip_bfloat16* BT    = (__hip_bfloat16*)p; p += (size_t)NT*G*NSTATE*2;
  __hip_bfloat16* y_bf  = (__hip_bfloat16*)p; p += (size_t)NT*DIN*2;
  float* dtb    = (float*)p;  p += (size_t)NT*NH*4;
  float* Acs    = (float*)p;  p += (size_t)BATCH*NH*NC*CS*4;
  float* dt_part = (float*)y_bf;     // aliases y_bf (dead until y_mfma)
  char* F = p;
  __hip_bfloat16* w_in_bf   = (__hip_bfloat16*)F;
  __hip_bfloat16* xsT       = (__hip_bfloat16*)F;
  __hip_bfloat16* xwT       = (__hip_bfloat16*)(F + 67108864);
  __hip_bfloat16* hs_bf     = (__hip_bfloat16*)(F + 150994944);
  __hip_bfloat16* states_bf = (__hip_bfloat16*)(F + 150994944);
  char* F2 = F + 150994944 + 33554432;
  __hip_bfloat16* w_out_bf  = (__hip_bfloat16*)F2;

  dt_gemm_splitk<<<dim3(DTSK, NT/128), 256, 0, stream>>>(hs, in_proj_w + (size_t)ZXW*HID, dt_part, hs_bf);
  dt_scan_kernel<<<BATCH*NH*NC, CS, 0, stream>>>(dt_part, dt_bias, A_log, dtb, Acs);

  cast2_kernel<<<4096, 256, 0, stream>>>(in_proj_w, w_in_bf, out_proj_w, w_out_bf);

  gemm_bf16_256<true><<<dim3((NT/256)*(ZXW/256)), 512, 0, stream>>>(
      hs_bf, w_in_bf, zx_bf, NT, ZXW, HID);

  conv_fused_kernel<<<dim3(NT/64, CONV_DIM/64), 256, 0, stream>>>(
      zx_bf, conv_w, conv_b, dtb, Acs, xsT, xwT, B_bf, C_bf, BT);

  chunk_states_fused<<<dim3(NH, BATCH), 256, 0, stream>>>(xwT, BT, Acs, states_bf);

  y_mfma_kernel<<<dim3(NH, BATCH*NC), 256, 0, stream>>>(zx_bf, C_bf, B_bf, xsT, states_bf, dtb, Acs, Dp, y_bf);
  groupnorm_bf16_kernel<<<NT*G, 256, 0, stream>>>((unsigned short*)y_bf, norm_w);

  gemm_bf16_256<false><<<dim3((NT/256)*(HID/256)), 512, 0, stream>>>(
      y_bf, w_out_bf, outp, NT, HID, DIN);
}